// Round 1
// baseline (1184.771 us; speedup 1.0000x reference)
//
#include <hip/hip_runtime.h>
#include <hip/hip_bf16.h>

typedef __hip_bfloat16 bf16;

// Problem constants
#define BB 2
#define NN 2048
#define CC 1024
#define HH 16
#define DD 64
#define MM (BB*NN)   // 4096

// ---------------------------------------------------------------------------
// Tiled GEMM: C[M x N] = A[M x K] * Bw[K x N] * scale
// A: TA (float or bf16), Bw: float, out: TO (bf16 or float)
// 64x64 tile, BK=16, block (16,16), each thread 4x4.
// ---------------------------------------------------------------------------
template<typename TA, typename TO>
__global__ __launch_bounds__(256) void gemm_kernel(const TA* __restrict__ A,
                                                   const float* __restrict__ Bw,
                                                   TO* __restrict__ Cm,
                                                   int M, int Nn, int K, float scale) {
    __shared__ float As[16][65];   // [k][m], pad to avoid write conflicts
    __shared__ float Bs[16][64];   // [k][n]
    const int tx = threadIdx.x, ty = threadIdx.y;
    const int tid = ty * 16 + tx;
    const int n0 = blockIdx.x * 64;
    const int m0 = blockIdx.y * 64;

    float acc[4][4] = {};

    for (int k0 = 0; k0 < K; k0 += 16) {
        // stage A tile (64 rows x 16 k)
        #pragma unroll
        for (int i = 0; i < 4; ++i) {
            int idx = tid + i * 256;          // 0..1023
            int m = idx >> 4, kk = idx & 15;
            As[kk][m] = (float)A[(size_t)(m0 + m) * K + k0 + kk];
        }
        // stage B tile (16 k x 64 n) — coalesced
        #pragma unroll
        for (int i = 0; i < 4; ++i) {
            int idx = tid + i * 256;
            int kk = idx >> 6, nn = idx & 63;
            Bs[kk][nn] = Bw[(size_t)(k0 + kk) * Nn + n0 + nn];
        }
        __syncthreads();
        #pragma unroll
        for (int kk = 0; kk < 16; ++kk) {
            float a[4], b[4];
            #pragma unroll
            for (int i = 0; i < 4; ++i) a[i] = As[kk][ty * 4 + i];
            #pragma unroll
            for (int j = 0; j < 4; ++j) b[j] = Bs[kk][tx * 4 + j];
            #pragma unroll
            for (int i = 0; i < 4; ++i)
                #pragma unroll
                for (int j = 0; j < 4; ++j)
                    acc[i][j] += a[i] * b[j];
        }
        __syncthreads();
    }
    #pragma unroll
    for (int i = 0; i < 4; ++i)
        #pragma unroll
        for (int j = 0; j < 4; ++j)
            Cm[(size_t)(m0 + ty * 4 + i) * Nn + n0 + tx * 4 + j] = (TO)(acc[i][j] * scale);
}

// ---------------------------------------------------------------------------
// RoPE, in place on bf16 [B*N, C] viewed as (B,N,H,D). One thread per (b,n,h,d<32)
// pair: q'[d]    = q[d]*cos[d]   - q[d+32]*sin[d]
//       q'[d+32] = q[d+32]*cos[d+32] + q[d]*sin[d+32]
// ---------------------------------------------------------------------------
__global__ __launch_bounds__(256) void rope_kernel(bf16* __restrict__ Qb,
                                                   const float* __restrict__ cosp,
                                                   const float* __restrict__ sinp) {
    int idx = blockIdx.x * 256 + threadIdx.x;    // B*N*H*32 total
    int d  = idx & 31;
    int h  = (idx >> 5) & (HH - 1);
    int nl = idx >> 9;                            // b*N + n, 0..4095
    size_t base = (size_t)nl * CC + h * DD + d;
    float q1 = (float)Qb[base];
    float q2 = (float)Qb[base + 32];
    float c1 = cosp[nl * DD + d],      s1 = sinp[nl * DD + d];
    float c2 = cosp[nl * DD + d + 32], s2 = sinp[nl * DD + d + 32];
    Qb[base]      = (bf16)(q1 * c1 - q2 * s1);
    Qb[base + 32] = (bf16)(q2 * c2 + q1 * s2);
}

// ---------------------------------------------------------------------------
// Flash attention (causal), fp32 VALU compute.
// Block (16,16) = 4 waves handles one (b, h, 64-row q tile).
// Q pre-scaled by D^-0.5 in the projection epilogue.
// ---------------------------------------------------------------------------
__global__ __launch_bounds__(256) void flash_kernel(const bf16* __restrict__ Qb,
                                                    const bf16* __restrict__ Kb,
                                                    const bf16* __restrict__ Vb,
                                                    bf16* __restrict__ Ab) {
    __shared__ float Qs[64][65];   // [d][r]
    __shared__ float Ks[64][65];   // [d][c]
    __shared__ float Vs[64][64];   // [c][d]
    __shared__ float Ps[64][65];   // [r][c]

    const int tx = threadIdx.x, ty = threadIdx.y;
    const int tid = ty * 16 + tx;
    const int bid = blockIdx.x;           // B*H*(N/64) = 1024
    const int qt = bid & 31;
    const int h  = (bid >> 5) & (HH - 1);
    const int b  = bid >> 9;
    const int q0 = qt * 64;

    // stage Q tile: Qs[d][r]
    #pragma unroll
    for (int i = 0; i < 16; ++i) {
        int idx = tid + i * 256;          // 4096
        int r = idx >> 6, d = idx & 63;
        Qs[d][r] = (float)Qb[((size_t)(b * NN + q0 + r)) * CC + h * DD + d];
    }

    float o[4][4] = {};
    float m[4], l[4];
    #pragma unroll
    for (int i = 0; i < 4; ++i) { m[i] = -1e30f; l[i] = 0.f; }

    for (int kt = 0; kt <= qt; ++kt) {
        const int k0 = kt * 64;
        __syncthreads();   // protect prior-iter Vs/Ps reads (and Qs staging on kt=0)
        #pragma unroll
        for (int i = 0; i < 16; ++i) {
            int idx = tid + i * 256;
            int c = idx >> 6, d = idx & 63;
            size_t g = ((size_t)(b * NN + k0 + c)) * CC + h * DD + d;
            Ks[d][c] = (float)Kb[g];
            Vs[c][d] = (float)Vb[g];
        }
        __syncthreads();

        // S = Q K^T  (4x4 per thread)
        float s[4][4] = {};
        for (int d = 0; d < 64; ++d) {
            float a[4], bb[4];
            #pragma unroll
            for (int i = 0; i < 4; ++i) a[i]  = Qs[d][ty * 4 + i];
            #pragma unroll
            for (int j = 0; j < 4; ++j) bb[j] = Ks[d][tx * 4 + j];
            #pragma unroll
            for (int i = 0; i < 4; ++i)
                #pragma unroll
                for (int j = 0; j < 4; ++j)
                    s[i][j] += a[i] * bb[j];
        }
        if (kt == qt) {   // diagonal tile: causal mask
            #pragma unroll
            for (int i = 0; i < 4; ++i)
                #pragma unroll
                for (int j = 0; j < 4; ++j)
                    if (k0 + tx * 4 + j > q0 + ty * 4 + i) s[i][j] = -1e30f;
        }

        // online softmax, row-wise (rows = ty*4+i, reduce across tx lanes)
        #pragma unroll
        for (int i = 0; i < 4; ++i) {
            float rm = fmaxf(fmaxf(s[i][0], s[i][1]), fmaxf(s[i][2], s[i][3]));
            #pragma unroll
            for (int off = 1; off < 16; off <<= 1) rm = fmaxf(rm, __shfl_xor(rm, off, 64));
            float mn = fmaxf(m[i], rm);
            float sc = __expf(m[i] - mn);
            float p[4], rs = 0.f;
            #pragma unroll
            for (int j = 0; j < 4; ++j) { p[j] = __expf(s[i][j] - mn); rs += p[j]; }
            #pragma unroll
            for (int off = 1; off < 16; off <<= 1) rs += __shfl_xor(rs, off, 64);
            m[i] = mn;
            l[i] = l[i] * sc + rs;
            #pragma unroll
            for (int j = 0; j < 4; ++j) { o[i][j] *= sc; Ps[ty * 4 + i][tx * 4 + j] = p[j]; }
        }
        __syncthreads();

        // O += P V
        for (int c = 0; c < 64; ++c) {
            float p[4], v[4];
            #pragma unroll
            for (int i = 0; i < 4; ++i) p[i] = Ps[ty * 4 + i][c];
            #pragma unroll
            for (int j = 0; j < 4; ++j) v[j] = Vs[c][tx * 4 + j];
            #pragma unroll
            for (int i = 0; i < 4; ++i)
                #pragma unroll
                for (int j = 0; j < 4; ++j)
                    o[i][j] += p[i] * v[j];
        }
    }

    #pragma unroll
    for (int i = 0; i < 4; ++i)
        #pragma unroll
        for (int j = 0; j < 4; ++j)
            Ab[((size_t)(b * NN + q0 + ty * 4 + i)) * CC + h * DD + tx * 4 + j] =
                (bf16)(o[i][j] / l[i]);
}

// ---------------------------------------------------------------------------
extern "C" void kernel_launch(void* const* d_in, const int* in_sizes, int n_in,
                              void* d_out, int out_size, void* d_ws, size_t ws_size,
                              hipStream_t stream) {
    const float* hs   = (const float*)d_in[0];
    const float* cosp = (const float*)d_in[1];
    const float* sinp = (const float*)d_in[2];
    const float* Wq   = (const float*)d_in[3];
    const float* Wk   = (const float*)d_in[4];
    const float* Wv   = (const float*)d_in[5];
    const float* Wo   = (const float*)d_in[6];
    float* out = (float*)d_out;

    char* ws = (char*)d_ws;
    const size_t SZ = (size_t)MM * CC * sizeof(bf16);   // 8 MB
    bf16* Qbuf = (bf16*)(ws);
    bf16* Kbuf = (bf16*)(ws + SZ);
    bf16* Vbuf = (bf16*)(ws + 2 * SZ);
    bf16* Abuf = (bf16*)(ws + 3 * SZ);

    dim3 blk(16, 16);
    dim3 ggrid(CC / 64, MM / 64);   // (16, 64)

    const float scaling = 0.125f;   // D^-0.5

    gemm_kernel<float, bf16><<<ggrid, blk, 0, stream>>>(hs, Wq, Qbuf, MM, CC, CC, scaling);
    gemm_kernel<float, bf16><<<ggrid, blk, 0, stream>>>(hs, Wk, Kbuf, MM, CC, CC, 1.0f);
    gemm_kernel<float, bf16><<<ggrid, blk, 0, stream>>>(hs, Wv, Vbuf, MM, CC, CC, 1.0f);

    int rope_threads = BB * NN * HH * 32;   // 2,097,152
    rope_kernel<<<rope_threads / 256, 256, 0, stream>>>(Qbuf, cosp, sinp);
    rope_kernel<<<rope_threads / 256, 256, 0, stream>>>(Kbuf, cosp, sinp);

    flash_kernel<<<BB * HH * (NN / 64), blk, 0, stream>>>(Qbuf, Kbuf, Vbuf, Abuf);

    gemm_kernel<bf16, float><<<ggrid, blk, 0, stream>>>(Abuf, Wo, out, MM, CC, CC, 1.0f);
}

// Round 2
// 283.776 us; speedup vs baseline: 4.1750x; 4.1750x over previous
//
#include <hip/hip_runtime.h>
#include <hip/hip_bf16.h>

typedef __hip_bfloat16 bf16;
typedef __attribute__((ext_vector_type(8))) short short8;
typedef __attribute__((ext_vector_type(4))) short short4v;
typedef __attribute__((ext_vector_type(4))) float f32x4;

#define BB 2
#define NN 2048
#define CC 1024
#define HH 16
#define DD 64
#define MM (BB*NN)     // 4096
#define QKVN 3072

// ---------------------------------------------------------------------------
// fp32 -> bf16 elementwise convert (4 elems / thread)
// ---------------------------------------------------------------------------
__global__ __launch_bounds__(256) void convert_f32_bf16(const float* __restrict__ in,
                                                        bf16* __restrict__ out) {
    int i = blockIdx.x * 256 + threadIdx.x;
    float4 v = ((const float4*)in)[i];
    bf16 b0 = (bf16)v.x, b1 = (bf16)v.y, b2 = (bf16)v.z, b3 = (bf16)v.w;
    short4v s;
    s.x = *(short*)&b0; s.y = *(short*)&b1; s.z = *(short*)&b2; s.w = *(short*)&b3;
    *((short4v*)out + i) = s;
}

// ---------------------------------------------------------------------------
// Transpose fp32 W[K=1024][N=1024] -> bf16 Wt[N][K] (LDS-tiled, coalesced both sides)
// ---------------------------------------------------------------------------
__global__ __launch_bounds__(256) void transpose_w(const float* __restrict__ W,
                                                   bf16* __restrict__ Wt) {
    __shared__ float t[32][33];
    const int tx = threadIdx.x, ty = threadIdx.y;
    const int x0 = blockIdx.x * 32, y0 = blockIdx.y * 32;   // x = n, y = k
    #pragma unroll
    for (int i = 0; i < 4; ++i)
        t[ty + i * 8][tx] = W[(size_t)(y0 + ty + i * 8) * CC + x0 + tx];
    __syncthreads();
    #pragma unroll
    for (int i = 0; i < 4; ++i)
        Wt[(size_t)(x0 + ty + i * 8) * CC + y0 + tx] = (bf16)t[tx][ty + i * 8];
}

// ---------------------------------------------------------------------------
// bf16 MFMA GEMM: C[M x Nn] = A[M x 1024] * Bt[Nn x 1024]^T
// 128x128 tile, BK=32, 4 waves (2x2), each wave 64x64 = 4x4 frags of 16x16x32.
// ROPE=true: epilogue applies q-scaling (cols<1024) and RoPE (cols<2048).
// ---------------------------------------------------------------------------
template<int Nn, bool ROPE, typename TO>
__global__ __launch_bounds__(256) void gemm_mfma(const bf16* __restrict__ A,
                                                 const bf16* __restrict__ Bt,
                                                 TO* __restrict__ Cm,
                                                 const float* __restrict__ cosp,
                                                 const float* __restrict__ sinp) {
    constexpr int K = 1024;
    __shared__ bf16 As[128][40];   // +8 pad: row stride 80B (16B-aligned, 2-way banks)
    __shared__ bf16 Bs[128][40];
    const int tid = threadIdx.x;
    const int lane = tid & 63, wid = tid >> 6;
    const int wr = wid >> 1, wc = wid & 1;
    const int n0 = blockIdx.x * 128, m0 = blockIdx.y * 128;
    const int l16 = lane & 15, lg = lane >> 4;

    f32x4 acc[4][4];
    #pragma unroll
    for (int i = 0; i < 4; ++i)
        #pragma unroll
        for (int j = 0; j < 4; ++j) acc[i][j] = {0.f, 0.f, 0.f, 0.f};

    for (int k0 = 0; k0 < K; k0 += 32) {
        __syncthreads();
        #pragma unroll
        for (int j = 0; j < 2; ++j) {
            int c = tid + j * 256;                  // 0..511
            int r = c >> 2, co = (c & 3) * 8;       // 128 rows x 32 cols
            *(short8*)&As[r][co] = *(const short8*)&A [(size_t)(m0 + r) * K + k0 + co];
            *(short8*)&Bs[r][co] = *(const short8*)&Bt[(size_t)(n0 + r) * K + k0 + co];
        }
        __syncthreads();
        short8 af[4], bf_[4];
        #pragma unroll
        for (int i = 0; i < 4; ++i) af[i]  = *(const short8*)&As[wr * 64 + i * 16 + l16][lg * 8];
        #pragma unroll
        for (int j = 0; j < 4; ++j) bf_[j] = *(const short8*)&Bs[wc * 64 + j * 16 + l16][lg * 8];
        #pragma unroll
        for (int i = 0; i < 4; ++i)
            #pragma unroll
            for (int j = 0; j < 4; ++j)
                acc[i][j] = __builtin_amdgcn_mfma_f32_16x16x32_bf16(af[i], bf_[j], acc[i][j], 0, 0, 0);
    }

    // Epilogue. D layout: row = lg*4 + r, col = l16 within each 16x16 frag.
    #pragma unroll
    for (int i = 0; i < 4; ++i) {
        #pragma unroll
        for (int r = 0; r < 4; ++r) {
            const int row = m0 + wr * 64 + i * 16 + lg * 4 + r;
            if (ROPE) {
                #pragma unroll
                for (int j = 0; j < 4; ++j) {
                    const int col = n0 + wc * 64 + j * 16 + l16;
                    float x = acc[i][j][r];
                    float y = acc[i][j ^ 2][r];     // the d +/- 32 partner (lane-local)
                    float ov;
                    if (col < 2 * CC) {             // q or k region: RoPE
                        const float qs = (col < CC) ? 0.125f : 1.0f;
                        const int d = col & 63;
                        const float cv = cosp[(size_t)row * DD + d];
                        const float sv = sinp[(size_t)row * DD + d];
                        ov = (d < 32) ? (x * cv - y * sv) * qs
                                      : (x * cv + y * sv) * qs;
                    } else {
                        ov = x;                     // v region
                    }
                    Cm[(size_t)row * Nn + col] = (TO)ov;
                }
            } else {
                #pragma unroll
                for (int j = 0; j < 4; ++j)
                    Cm[(size_t)row * Nn + n0 + wc * 64 + j * 16 + l16] = (TO)acc[i][j][r];
            }
        }
    }
}

// ---------------------------------------------------------------------------
// MFMA flash attention (causal). 4 waves/block; wave w owns q-rows [wq0, wq0+16).
// KV tiles of 64 staged in LDS; V stored transposed [d][k]; P re-laid-out via
// wave-private padded LDS.  Q pre-scaled by D^-0.5 in the projection epilogue.
// ---------------------------------------------------------------------------
__global__ __launch_bounds__(256) void flash_mfma(const bf16* __restrict__ QKV,
                                                  bf16* __restrict__ Ab) {
    __shared__ bf16 Ks[64][72];        // [k][d] +8 pad
    __shared__ bf16 Vt[64][72];        // [d][k] +8 pad
    __shared__ bf16 Ps[4][16][72];     // per-wave [q][k] +8 pad

    const int tid = threadIdx.x;
    const int lane = tid & 63, wid = tid >> 6;
    const int l16 = lane & 15, lg = lane >> 4;
    const int bid = blockIdx.x;                 // B*H*32 = 1024
    const int qt = bid & 31, h = (bid >> 5) & 15, b = bid >> 9;
    const int q0 = qt * 64;
    const int wq0 = q0 + wid * 16;

    // Q fragments for this wave's 16 rows (2 x K=32 chunks), direct from global
    short8 qf[2];
    const size_t qbase = (size_t)(b * NN + wq0 + l16) * QKVN + h * DD + lg * 8;
    qf[0] = *(const short8*)&QKV[qbase];
    qf[1] = *(const short8*)&QKV[qbase + 32];

    f32x4 o[4];
    #pragma unroll
    for (int dc = 0; dc < 4; ++dc) o[dc] = {0.f, 0.f, 0.f, 0.f};
    float m[4], l[4];
    #pragma unroll
    for (int r = 0; r < 4; ++r) { m[r] = -1e30f; l[r] = 0.f; }

    for (int kt = 0; kt <= qt; ++kt) {
        const int k0 = kt * 64;
        __syncthreads();                        // prior tile's LDS reads done
        #pragma unroll
        for (int j = 0; j < 2; ++j) {
            int cc = tid + 256 * j;             // 0..511
            int r = cc >> 3, c8 = (cc & 7) * 8; // 64 rows x 8 chunks
            size_t gb = (size_t)(b * NN + k0 + r) * QKVN + h * DD;
            *(short8*)&Ks[r][c8] = *(const short8*)&QKV[gb + CC + c8];
            short8 vv = *(const short8*)&QKV[gb + 2 * CC + c8];
            #pragma unroll
            for (int e = 0; e < 8; ++e) Vt[c8 + e][r] = ((const bf16*)&vv)[e];
        }
        __syncthreads();

        if (k0 <= wq0 + 15) {                   // wave-uniform: tile has unmasked elems
            // S = Q K^T : 4 k-chunks of 16, D layout row=q (lg*4+r), col=k (l16)
            f32x4 s[4];
            #pragma unroll
            for (int c = 0; c < 4; ++c) {
                s[c] = {0.f, 0.f, 0.f, 0.f};
                #pragma unroll
                for (int ch = 0; ch < 2; ++ch) {
                    short8 kf = *(const short8*)&Ks[c * 16 + l16][lg * 8 + ch * 32];
                    s[c] = __builtin_amdgcn_mfma_f32_16x16x32_bf16(qf[ch], kf, s[c], 0, 0, 0);
                }
            }
            if (k0 + 63 > wq0) {                // diagonal-ish: causal mask
                #pragma unroll
                for (int c = 0; c < 4; ++c)
                    #pragma unroll
                    for (int r = 0; r < 4; ++r)
                        if (k0 + c * 16 + l16 > wq0 + lg * 4 + r) s[c][r] = -1e30f;
            }
            // online softmax per q-row (reduce over k: 4 regs + 16 lanes of group)
            #pragma unroll
            for (int r = 0; r < 4; ++r) {
                float rm = fmaxf(fmaxf(s[0][r], s[1][r]), fmaxf(s[2][r], s[3][r]));
                rm = fmaxf(rm, __shfl_xor(rm, 1, 64));
                rm = fmaxf(rm, __shfl_xor(rm, 2, 64));
                rm = fmaxf(rm, __shfl_xor(rm, 4, 64));
                rm = fmaxf(rm, __shfl_xor(rm, 8, 64));
                float mn = fmaxf(m[r], rm);
                float sc = __expf(m[r] - mn);
                float rs = 0.f;
                #pragma unroll
                for (int c = 0; c < 4; ++c) { float p = __expf(s[c][r] - mn); s[c][r] = p; rs += p; }
                rs += __shfl_xor(rs, 1, 64);
                rs += __shfl_xor(rs, 2, 64);
                rs += __shfl_xor(rs, 4, 64);
                rs += __shfl_xor(rs, 8, 64);
                m[r] = mn;
                l[r] = l[r] * sc + rs;
                #pragma unroll
                for (int dc = 0; dc < 4; ++dc) o[dc][r] *= sc;
                #pragma unroll
                for (int c = 0; c < 4; ++c) Ps[wid][lg * 4 + r][c * 16 + l16] = (bf16)s[c][r];
            }
            asm volatile("s_waitcnt lgkmcnt(0)" ::: "memory");   // cross-lane P visibility
            __builtin_amdgcn_sched_barrier(0);
            // O += P V  (A = P from Ps, B = V^T rows = d)
            #pragma unroll
            for (int pc = 0; pc < 2; ++pc) {
                short8 pf = *(const short8*)&Ps[wid][l16][lg * 8 + pc * 32];
                #pragma unroll
                for (int dc = 0; dc < 4; ++dc) {
                    short8 vf = *(const short8*)&Vt[dc * 16 + l16][lg * 8 + pc * 32];
                    o[dc] = __builtin_amdgcn_mfma_f32_16x16x32_bf16(pf, vf, o[dc], 0, 0, 0);
                }
            }
        }
    }

    #pragma unroll
    for (int dc = 0; dc < 4; ++dc)
        #pragma unroll
        for (int r = 0; r < 4; ++r)
            Ab[(size_t)(b * NN + wq0 + lg * 4 + r) * CC + h * DD + dc * 16 + l16] =
                (bf16)(o[dc][r] / l[r]);
}

// ---------------------------------------------------------------------------
extern "C" void kernel_launch(void* const* d_in, const int* in_sizes, int n_in,
                              void* d_out, int out_size, void* d_ws, size_t ws_size,
                              hipStream_t stream) {
    const float* hs   = (const float*)d_in[0];
    const float* cosp = (const float*)d_in[1];
    const float* sinp = (const float*)d_in[2];
    const float* Wq   = (const float*)d_in[3];
    const float* Wk   = (const float*)d_in[4];
    const float* Wv   = (const float*)d_in[5];
    const float* Wo   = (const float*)d_in[6];
    float* out = (float*)d_out;

    char* ws = (char*)d_ws;
    bf16* hsb   = (bf16*)(ws);                    //  8 MB  [4096][1024]
    bf16* Wtqkv = (bf16*)(ws + (8  << 20));       //  6 MB  [3072][1024]
    bf16* Wto   = (bf16*)(ws + (14 << 20));       //  2 MB  [1024][1024]
    bf16* QKV   = (bf16*)(ws + (16 << 20));       // 24 MB  [4096][3072]
    bf16* Abuf  = (bf16*)(ws + (40 << 20));       //  8 MB  [4096][1024]

    convert_f32_bf16<<<MM * CC / 1024, 256, 0, stream>>>(hs, hsb);

    dim3 tb(32, 8), tg(32, 32);
    transpose_w<<<tg, tb, 0, stream>>>(Wq, Wtqkv);
    transpose_w<<<tg, tb, 0, stream>>>(Wk, Wtqkv + (1 << 20));
    transpose_w<<<tg, tb, 0, stream>>>(Wv, Wtqkv + (2 << 20));
    transpose_w<<<tg, tb, 0, stream>>>(Wo, Wto);

    gemm_mfma<QKVN, true, bf16><<<dim3(QKVN / 128, MM / 128), 256, 0, stream>>>(
        hsb, Wtqkv, QKV, cosp, sinp);

    flash_mfma<<<BB * HH * (NN / 64), 256, 0, stream>>>(QKV, Abuf);

    gemm_mfma<CC, false, float><<<dim3(CC / 128, MM / 128), 256, 0, stream>>>(
        Abuf, Wto, out, nullptr, nullptr);
}

// Round 3
// 177.862 us; speedup vs baseline: 6.6612x; 1.5955x over previous
//
#include <hip/hip_runtime.h>
#include <hip/hip_bf16.h>

typedef __hip_bfloat16 bf16;
typedef __attribute__((ext_vector_type(8))) short short8;
typedef __attribute__((ext_vector_type(4))) short short4v;
typedef __attribute__((ext_vector_type(4))) float f32x4;

#define BB 2
#define NN 2048
#define CC 1024
#define HH 16
#define DD 64
#define MM (BB*NN)     // 4096
#define QKVN 3072
#define LOG2E 1.44269504088896340736f

__device__ __forceinline__ void glds16(const void* g, void* l) {
    __builtin_amdgcn_global_load_lds((const __attribute__((address_space(1))) void*)g,
                                     (__attribute__((address_space(3))) void*)l, 16, 0, 0);
}
__device__ __forceinline__ short pkbf(float x) { bf16 t = (bf16)x; return *(short*)&t; }

// ---------------------------------------------------------------------------
__global__ __launch_bounds__(256) void convert_f32_bf16(const float* __restrict__ in,
                                                        bf16* __restrict__ out) {
    int i = blockIdx.x * 256 + threadIdx.x;
    float4 v = ((const float4*)in)[i];
    short4v s;
    s.x = pkbf(v.x); s.y = pkbf(v.y); s.z = pkbf(v.z); s.w = pkbf(v.w);
    *((short4v*)out + i) = s;
}

// Transpose fp32 W[K][N] -> bf16 Wt[N][K]; z selects among 3 weights
__global__ __launch_bounds__(256) void transpose3(const float* __restrict__ W0,
                                                  const float* __restrict__ W1,
                                                  const float* __restrict__ W2,
                                                  bf16* __restrict__ Wt) {
    __shared__ float t[32][33];
    const float* W = blockIdx.z == 0 ? W0 : (blockIdx.z == 1 ? W1 : W2);
    bf16* dst = Wt + (size_t)blockIdx.z * CC * CC;
    const int tx = threadIdx.x, ty = threadIdx.y;
    const int x0 = blockIdx.x * 32, y0 = blockIdx.y * 32;
    #pragma unroll
    for (int i = 0; i < 4; ++i)
        t[ty + i * 8][tx] = W[(size_t)(y0 + ty + i * 8) * CC + x0 + tx];
    __syncthreads();
    #pragma unroll
    for (int i = 0; i < 4; ++i)
        dst[(size_t)(x0 + ty + i * 8) * CC + y0 + tx] = (bf16)t[tx][ty + i * 8];
}

// ---------------------------------------------------------------------------
// m97-style bf16 MFMA GEMM: C[M x Nn] = A[M x 1024] @ Bt[Nn x 1024]^T
// MODE 1: QKV epilogue (RoPE+log2e-scale on q/k cols; V written transposed to VtOut)
// MODE 2: fp32 output (out-projection)
// ---------------------------------------------------------------------------
template<int Nn, int MODE>
__global__ __launch_bounds__(256) void gemm2(const bf16* __restrict__ A,
                                             const bf16* __restrict__ Bt,
                                             void* __restrict__ Cout,
                                             const float* __restrict__ cosp,
                                             const float* __restrict__ sinp,
                                             bf16* __restrict__ VtOut) {
    __shared__ __align__(16) bf16 As[128 * 32];
    __shared__ __align__(16) bf16 Bs[128 * 32];
    const int tid = threadIdx.x, lane = tid & 63, wid = tid >> 6;
    const int wr = wid >> 1, wc = wid & 1, l16 = lane & 15, lg = lane >> 4;
    const int n0 = blockIdx.x * 128, m0 = blockIdx.y * 128;

    f32x4 acc[4][4];
    #pragma unroll
    for (int i = 0; i < 4; ++i)
        #pragma unroll
        for (int j = 0; j < 4; ++j) acc[i][j] = {0.f, 0.f, 0.f, 0.f};

    for (int k0 = 0; k0 < 1024; k0 += 32) {
        #pragma unroll
        for (int ii = 0; ii < 2; ++ii) {
            const int issue = wid * 2 + ii;
            const int a = issue * 1024 + lane * 16;
            const int r = a >> 6, cb = a & 63;
            glds16(&A [(size_t)(m0 + r) * 1024 + k0 + (cb >> 1)], (char*)As + issue * 1024);
            glds16(&Bt[(size_t)(n0 + r) * 1024 + k0 + (cb >> 1)], (char*)Bs + issue * 1024);
        }
        __syncthreads();     // drains vmcnt (staging) before reads
        short8 af[4], bfr[4];
        #pragma unroll
        for (int i = 0; i < 4; ++i) af[i]  = *(const short8*)((char*)As + (wr * 64 + i * 16 + l16) * 64 + lg * 16);
        #pragma unroll
        for (int j = 0; j < 4; ++j) bfr[j] = *(const short8*)((char*)Bs + (wc * 64 + j * 16 + l16) * 64 + lg * 16);
        #pragma unroll
        for (int i = 0; i < 4; ++i)
            #pragma unroll
            for (int j = 0; j < 4; ++j)
                acc[i][j] = __builtin_amdgcn_mfma_f32_16x16x32_bf16(af[i], bfr[j], acc[i][j], 0, 0, 0);
        __syncthreads();     // reads done before next-iter staging
    }

    if (MODE == 1 && n0 >= 2 * CC) {
        // V region: write transposed Vt[b][h][d][n], 8B stores
        #pragma unroll
        for (int i = 0; i < 4; ++i) {
            const int row0 = m0 + wr * 64 + i * 16 + lg * 4;
            const int bb = row0 >> 11, nn_ = row0 & (NN - 1);
            #pragma unroll
            for (int j = 0; j < 4; ++j) {
                const int col = n0 - 2 * CC + wc * 64 + j * 16 + l16;   // 0..1023
                const int hh = col >> 6, d = col & 63;
                short4v s4;
                #pragma unroll
                for (int r = 0; r < 4; ++r) s4[r] = pkbf(acc[i][j][r]);
                *(short4v*)&VtOut[((size_t)(bb * HH + hh) * DD + d) * NN + nn_] = s4;
            }
        }
    } else if (MODE == 1) {
        // q/k region: RoPE; q additionally scaled by D^-0.5 * log2(e)
        const float qs = (n0 < CC) ? 0.125f * LOG2E : 1.0f;
        bf16* Cb = (bf16*)Cout;
        #pragma unroll
        for (int i = 0; i < 4; ++i)
            #pragma unroll
            for (int r = 0; r < 4; ++r) {
                const int row = m0 + wr * 64 + i * 16 + lg * 4 + r;
                #pragma unroll
                for (int j = 0; j < 4; ++j) {
                    const int col = n0 + wc * 64 + j * 16 + l16;
                    const int d = col & 63;
                    const float cv = cosp[(size_t)row * DD + d];
                    const float sv = sinp[(size_t)row * DD + d];
                    const float x = acc[i][j][r], y = acc[i][j ^ 2][r];
                    const float ov = (d < 32) ? (x * cv - y * sv) * qs
                                              : (x * cv + y * sv) * qs;
                    Cb[(size_t)row * QKVN + col] = (bf16)ov;
                }
            }
    } else {
        float* Cf = (float*)Cout;
        #pragma unroll
        for (int i = 0; i < 4; ++i)
            #pragma unroll
            for (int r = 0; r < 4; ++r) {
                const int row = m0 + wr * 64 + i * 16 + lg * 4 + r;
                #pragma unroll
                for (int j = 0; j < 4; ++j)
                    Cf[(size_t)row * Nn + n0 + wc * 64 + j * 16 + l16] = acc[i][j][r];
            }
    }
}

// ---------------------------------------------------------------------------
// Flash attention v2: QBLK=128 (4 waves x 32 rows), KVBLK=64, double-buffered
// swizzled LDS K/V^T, swapped QK^T (S^T), in-register P -> PV via 16x16x16 MFMA.
// Q pre-scaled by D^-0.5*log2e; softmax in exp2 domain.
// ---------------------------------------------------------------------------
__global__ __launch_bounds__(256) void flash_mfma2(const bf16* __restrict__ QKV,
                                                   const bf16* __restrict__ Vt,
                                                   bf16* __restrict__ Ab) {
    __shared__ __align__(16) bf16 Ks[2][4096];
    __shared__ __align__(16) bf16 Vs[2][4096];
    const int tid = threadIdx.x, lane = tid & 63, wid = tid >> 6;
    const int l16 = lane & 15, lg = lane >> 4;
    const int bid = blockIdx.x;
    const int qt = 15 - (bid & 15);            // heavy tiles first
    const int bh = bid >> 4, h = bh & (HH - 1), b = bh >> 4;
    const int q0 = qt * 128;
    const int wq0 = q0 + wid * 32;
    const int nkt = 2 * qt + 2;

    const bf16* Kbase = QKV + (size_t)b * NN * QKVN + CC + h * DD;  // + k*QKVN
    const bf16* Vbase = Vt + (size_t)(b * HH + h) * DD * NN;        // + d*NN + k

    // Q fragments (rows wq0+qm*16+l16, k-chunks of 32)
    short8 qf[2][2];
    #pragma unroll
    for (int qm = 0; qm < 2; ++qm)
        #pragma unroll
        for (int ch = 0; ch < 2; ++ch)
            qf[qm][ch] = *(const short8*)&QKV[(size_t)(b * NN + wq0 + qm * 16 + l16) * QKVN
                                              + h * DD + ch * 32 + lg * 8];

    f32x4 o[4][2];
    #pragma unroll
    for (int dn = 0; dn < 4; ++dn)
        #pragma unroll
        for (int qm = 0; qm < 2; ++qm) o[dn][qm] = {0.f, 0.f, 0.f, 0.f};
    float mx[2] = {-1e30f, -1e30f}, ls[2] = {0.f, 0.f};

    auto stage = [&](int kt, int bufi) {
        const int k0s = kt * 64;
        #pragma unroll
        for (int ii = 0; ii < 2; ++ii) {
            const int issue = wid * 2 + ii;
            const int a = issue * 1024 + lane * 16;
            const int r = a >> 7;
            const int cb = (a & 127) ^ ((r & 7) << 4);   // pre-swizzled source
            glds16(Kbase + (size_t)(k0s + r) * QKVN + (cb >> 1), (char*)&Ks[bufi][0] + issue * 1024);
            glds16(Vbase + (size_t)r * NN + k0s + (cb >> 1),     (char*)&Vs[bufi][0] + issue * 1024);
        }
    };

    stage(0, 0);
    __syncthreads();

    for (int kt = 0; kt < nkt; ++kt) {
        const int k0 = kt * 64;
        const int cur = kt & 1;
        if (kt + 1 < nkt) stage(kt + 1, cur ^ 1);

        if (k0 < wq0 + 32) {                       // wave-uniform causal skip
            // ---- S^T = K Q^T ----
            f32x4 st[4][2];
            #pragma unroll
            for (int kc = 0; kc < 4; ++kc)
                #pragma unroll
                for (int qm = 0; qm < 2; ++qm) st[kc][qm] = {0.f, 0.f, 0.f, 0.f};
            __builtin_amdgcn_s_setprio(1);
            #pragma unroll
            for (int kc = 0; kc < 4; ++kc) {
                const int row = kc * 16 + l16;
                const char* rb = (const char*)&Ks[cur][0] + row * 128;
                const int sw = (row & 7) << 4;
                short8 kf0 = *(const short8*)(rb + ((lg * 16) ^ sw));
                short8 kf1 = *(const short8*)(rb + ((64 + lg * 16) ^ sw));
                #pragma unroll
                for (int qm = 0; qm < 2; ++qm) {
                    st[kc][qm] = __builtin_amdgcn_mfma_f32_16x16x32_bf16(kf0, qf[qm][0], st[kc][qm], 0, 0, 0);
                    st[kc][qm] = __builtin_amdgcn_mfma_f32_16x16x32_bf16(kf1, qf[qm][1], st[kc][qm], 0, 0, 0);
                }
            }
            __builtin_amdgcn_s_setprio(0);
            // ---- causal mask ----
            if (k0 + 63 > wq0) {
                #pragma unroll
                for (int kc = 0; kc < 4; ++kc)
                    #pragma unroll
                    for (int qm = 0; qm < 2; ++qm)
                        #pragma unroll
                        for (int r = 0; r < 4; ++r)
                            if (k0 + kc * 16 + lg * 4 + r > wq0 + qm * 16 + l16)
                                st[kc][qm][r] = -1e30f;
            }
            // ---- online softmax (per q-col of S^T; reduce 16 regs + lanes ^16,^32) ----
            float scs[2];
            #pragma unroll
            for (int qm = 0; qm < 2; ++qm) {
                float rm = -1e30f;
                #pragma unroll
                for (int kc = 0; kc < 4; ++kc)
                    #pragma unroll
                    for (int r = 0; r < 4; ++r) rm = fmaxf(rm, st[kc][qm][r]);
                rm = fmaxf(rm, __shfl_xor(rm, 16, 64));
                rm = fmaxf(rm, __shfl_xor(rm, 32, 64));
                const float mn = fmaxf(mx[qm], rm);
                const float sc = exp2f(mx[qm] - mn);
                float rs = 0.f;
                #pragma unroll
                for (int kc = 0; kc < 4; ++kc)
                    #pragma unroll
                    for (int r = 0; r < 4; ++r) {
                        const float p = exp2f(st[kc][qm][r] - mn);
                        st[kc][qm][r] = p; rs += p;
                    }
                rs += __shfl_xor(rs, 16, 64);
                rs += __shfl_xor(rs, 32, 64);
                mx[qm] = mn; ls[qm] = ls[qm] * sc + rs; scs[qm] = sc;
            }
            #pragma unroll
            for (int dn = 0; dn < 4; ++dn)
                #pragma unroll
                for (int qm = 0; qm < 2; ++qm) {
                    o[dn][qm][0] *= scs[qm]; o[dn][qm][1] *= scs[qm];
                    o[dn][qm][2] *= scs[qm]; o[dn][qm][3] *= scs[qm];
                }
            // ---- O^T += V^T P^T  (16x16x16, k = lg*4+e matches S^T rows) ----
            __builtin_amdgcn_s_setprio(1);
            #pragma unroll
            for (int kc = 0; kc < 4; ++kc) {
                short4v pf[2];
                #pragma unroll
                for (int qm = 0; qm < 2; ++qm) {
                    pf[qm][0] = pkbf(st[kc][qm][0]); pf[qm][1] = pkbf(st[kc][qm][1]);
                    pf[qm][2] = pkbf(st[kc][qm][2]); pf[qm][3] = pkbf(st[kc][qm][3]);
                }
                #pragma unroll
                for (int dn = 0; dn < 4; ++dn) {
                    const int row = dn * 16 + l16;
                    short4v vf = *(const short4v*)((const char*)&Vs[cur][0] + row * 128
                                                   + ((kc * 32 + lg * 8) ^ ((row & 7) << 4)));
                    o[dn][0] = __builtin_amdgcn_mfma_f32_16x16x16bf16_1k(vf, pf[0], o[dn][0], 0, 0, 0);
                    o[dn][1] = __builtin_amdgcn_mfma_f32_16x16x16bf16_1k(vf, pf[1], o[dn][1], 0, 0, 0);
                }
            }
            __builtin_amdgcn_s_setprio(0);
        }
        __syncthreads();      // drains staging vmcnt; next tile ready
    }

    // ---- epilogue: O^T[d][q]/l -> Ab[q][d], 8B stores ----
    #pragma unroll
    for (int qm = 0; qm < 2; ++qm) {
        const float inv = 1.f / ls[qm];
        const size_t rowb = (size_t)(b * NN + wq0 + qm * 16 + l16) * CC + h * DD;
        #pragma unroll
        for (int dn = 0; dn < 4; ++dn) {
            short4v s4;
            s4[0] = pkbf(o[dn][qm][0] * inv); s4[1] = pkbf(o[dn][qm][1] * inv);
            s4[2] = pkbf(o[dn][qm][2] * inv); s4[3] = pkbf(o[dn][qm][3] * inv);
            *(short4v*)&Ab[rowb + dn * 16 + lg * 4] = s4;
        }
    }
}

// ---------------------------------------------------------------------------
extern "C" void kernel_launch(void* const* d_in, const int* in_sizes, int n_in,
                              void* d_out, int out_size, void* d_ws, size_t ws_size,
                              hipStream_t stream) {
    const float* hs   = (const float*)d_in[0];
    const float* cosp = (const float*)d_in[1];
    const float* sinp = (const float*)d_in[2];
    const float* Wq   = (const float*)d_in[3];
    const float* Wk   = (const float*)d_in[4];
    const float* Wv   = (const float*)d_in[5];
    const float* Wo   = (const float*)d_in[6];
    float* out = (float*)d_out;

    char* ws = (char*)d_ws;
    bf16* hsb   = (bf16*)(ws);                    //  8 MB [4096][1024]
    bf16* Wtqkv = (bf16*)(ws + (8  << 20));       //  6 MB [3072][1024]
    bf16* Wto   = (bf16*)(ws + (14 << 20));       //  2 MB [1024][1024]
    bf16* QKV   = (bf16*)(ws + (16 << 20));       // 24 MB [4096][3072] (q,k cols used)
    bf16* Vtb   = (bf16*)(ws + (40 << 20));       //  8 MB [2][16][64][2048]
    bf16* Abuf  = hsb;                            // alias: hs consumed by QKV GEMM

    convert_f32_bf16<<<MM * CC / 1024, 256, 0, stream>>>(hs, hsb);

    dim3 tb(32, 8);
    transpose3<<<dim3(32, 32, 3), tb, 0, stream>>>(Wq, Wk, Wv, Wtqkv);
    transpose3<<<dim3(32, 32, 1), tb, 0, stream>>>(Wo, Wo, Wo, Wto);

    gemm2<QKVN, 1><<<dim3(QKVN / 128, MM / 128), 256, 0, stream>>>(
        hsb, Wtqkv, QKV, cosp, sinp, Vtb);

    flash_mfma2<<<BB * HH * (NN / 128), 256, 0, stream>>>(QKV, Vtb, Abuf);

    gemm2<CC, 2><<<dim3(CC / 128, MM / 128), 256, 0, stream>>>(
        Abuf, Wto, out, nullptr, nullptr, nullptr);
}

// Round 4
// 139.141 us; speedup vs baseline: 8.5149x; 1.2783x over previous
//
#include <hip/hip_runtime.h>
#include <hip/hip_bf16.h>

typedef __hip_bfloat16 bf16;
typedef __attribute__((ext_vector_type(8))) short short8;
typedef __attribute__((ext_vector_type(4))) short short4v;
typedef __attribute__((ext_vector_type(4))) float f32x4;

#define BB 2
#define NN 2048
#define CC 1024
#define HH 16
#define DD 64
#define MM (BB*NN)     // 4096
#define QKVN 3072
#define LOG2E 1.44269504088896340736f

__device__ __forceinline__ void glds16(const void* g, void* l) {
    __builtin_amdgcn_global_load_lds((const __attribute__((address_space(1))) void*)g,
                                     (__attribute__((address_space(3))) void*)l, 16, 0, 0);
}
__device__ __forceinline__ short pkbf(float x) { bf16 t = (bf16)x; return *(short*)&t; }

// ---------------------------------------------------------------------------
__global__ __launch_bounds__(256) void convert_f32_bf16(const float* __restrict__ in,
                                                        bf16* __restrict__ out) {
    int i = blockIdx.x * 256 + threadIdx.x;
    float4 v = ((const float4*)in)[i];
    short4v s;
    s.x = pkbf(v.x); s.y = pkbf(v.y); s.z = pkbf(v.z); s.w = pkbf(v.w);
    *((short4v*)out + i) = s;
}

// Transpose fp32 W[K][N] -> bf16 Wt[N][K]; z in 0..3 selects Wq,Wk,Wv,Wo
__global__ __launch_bounds__(256) void transpose4(const float* __restrict__ W0,
                                                  const float* __restrict__ W1,
                                                  const float* __restrict__ W2,
                                                  const float* __restrict__ W3,
                                                  bf16* __restrict__ Wtqkv,
                                                  bf16* __restrict__ Wto) {
    __shared__ float t[32][33];
    const int z = blockIdx.z;
    const float* W = z == 0 ? W0 : (z == 1 ? W1 : (z == 2 ? W2 : W3));
    bf16* dst = z < 3 ? Wtqkv + (size_t)z * CC * CC : Wto;
    const int tx = threadIdx.x, ty = threadIdx.y;
    const int x0 = blockIdx.x * 32, y0 = blockIdx.y * 32;
    #pragma unroll
    for (int i = 0; i < 4; ++i)
        t[ty + i * 8][tx] = W[(size_t)(y0 + ty + i * 8) * CC + x0 + tx];
    __syncthreads();
    #pragma unroll
    for (int i = 0; i < 4; ++i)
        dst[(size_t)(x0 + ty + i * 8) * CC + y0 + tx] = (bf16)t[tx][ty + i * 8];
}

// ---------------------------------------------------------------------------
// m97-style bf16 MFMA GEMM with XCD-aware swizzle.
// MODE 1: QKV epilogue (RoPE+log2e on q/k cols; V written transposed to VtOut)
// MODE 2: fp32 output (out-projection)
// ---------------------------------------------------------------------------
template<int Nn, int MODE>
__global__ __launch_bounds__(256) void gemm2(const bf16* __restrict__ A,
                                             const bf16* __restrict__ Bt,
                                             void* __restrict__ Cout,
                                             const float* __restrict__ cosp,
                                             const float* __restrict__ sinp,
                                             bf16* __restrict__ VtOut) {
    __shared__ __align__(16) bf16 As[128 * 32];
    __shared__ __align__(16) bf16 Bs[128 * 32];
    const int tid = threadIdx.x, lane = tid & 63, wid = tid >> 6;
    const int wr = wid >> 1, wc = wid & 1, l16 = lane & 15, lg = lane >> 4;
    // T1 XCD swizzle (nwg % 8 == 0 for both instantiations)
    constexpr int GX = Nn / 128;
    constexpr int GY = MM / 128;
    constexpr int CPX = GX * GY / 8;
    const int flat = blockIdx.y * GX + blockIdx.x;
    const int v = (flat & 7) * CPX + (flat >> 3);
    const int n0 = (v % GX) * 128, m0 = (v / GX) * 128;

    f32x4 acc[4][4];
    #pragma unroll
    for (int i = 0; i < 4; ++i)
        #pragma unroll
        for (int j = 0; j < 4; ++j) acc[i][j] = {0.f, 0.f, 0.f, 0.f};

    for (int k0 = 0; k0 < 1024; k0 += 32) {
        #pragma unroll
        for (int ii = 0; ii < 2; ++ii) {
            const int issue = wid * 2 + ii;
            const int a = issue * 1024 + lane * 16;
            const int r = a >> 6, cb = a & 63;
            glds16(&A [(size_t)(m0 + r) * 1024 + k0 + (cb >> 1)], (char*)As + issue * 1024);
            glds16(&Bt[(size_t)(n0 + r) * 1024 + k0 + (cb >> 1)], (char*)Bs + issue * 1024);
        }
        __syncthreads();     // drains vmcnt (staging) before reads
        short8 af[4], bfr[4];
        #pragma unroll
        for (int i = 0; i < 4; ++i) af[i]  = *(const short8*)((char*)As + (wr * 64 + i * 16 + l16) * 64 + lg * 16);
        #pragma unroll
        for (int j = 0; j < 4; ++j) bfr[j] = *(const short8*)((char*)Bs + (wc * 64 + j * 16 + l16) * 64 + lg * 16);
        #pragma unroll
        for (int i = 0; i < 4; ++i)
            #pragma unroll
            for (int j = 0; j < 4; ++j)
                acc[i][j] = __builtin_amdgcn_mfma_f32_16x16x32_bf16(af[i], bfr[j], acc[i][j], 0, 0, 0);
        __syncthreads();     // reads done before next-iter staging
    }

    if (MODE == 1 && n0 >= 2 * CC) {
        // V region: write transposed Vt[b][h][d][n], 8B stores
        #pragma unroll
        for (int i = 0; i < 4; ++i) {
            const int row0 = m0 + wr * 64 + i * 16 + lg * 4;
            const int bb = row0 >> 11, nn_ = row0 & (NN - 1);
            #pragma unroll
            for (int j = 0; j < 4; ++j) {
                const int col = n0 - 2 * CC + wc * 64 + j * 16 + l16;   // 0..1023
                const int hh = col >> 6, d = col & 63;
                short4v s4;
                #pragma unroll
                for (int r = 0; r < 4; ++r) s4[r] = pkbf(acc[i][j][r]);
                *(short4v*)&VtOut[((size_t)(bb * HH + hh) * DD + d) * NN + nn_] = s4;
            }
        }
    } else if (MODE == 1) {
        // q/k region: RoPE; q additionally scaled by D^-0.5 * log2(e)
        const float qs = (n0 < CC) ? 0.125f * LOG2E : 1.0f;
        bf16* Cb = (bf16*)Cout;
        #pragma unroll
        for (int i = 0; i < 4; ++i)
            #pragma unroll
            for (int r = 0; r < 4; ++r) {
                const int row = m0 + wr * 64 + i * 16 + lg * 4 + r;
                #pragma unroll
                for (int j = 0; j < 4; ++j) {
                    const int col = n0 + wc * 64 + j * 16 + l16;
                    const int d = col & 63;
                    const float cv = cosp[(size_t)row * DD + d];
                    const float sv = sinp[(size_t)row * DD + d];
                    const float x = acc[i][j][r], y = acc[i][j ^ 2][r];
                    const float ov = (d < 32) ? (x * cv - y * sv) * qs
                                              : (x * cv + y * sv) * qs;
                    Cb[(size_t)row * QKVN + col] = (bf16)ov;
                }
            }
    } else {
        float* Cf = (float*)Cout;
        #pragma unroll
        for (int i = 0; i < 4; ++i)
            #pragma unroll
            for (int r = 0; r < 4; ++r) {
                const int row = m0 + wr * 64 + i * 16 + lg * 4 + r;
                #pragma unroll
                for (int j = 0; j < 4; ++j)
                    Cf[(size_t)row * Nn + n0 + wc * 64 + j * 16 + l16] = acc[i][j][r];
            }
    }
}

// ---------------------------------------------------------------------------
// Flash attention v3: one 64-row q-tile per block, 4 waves x 16 q-rows,
// KVBLK=64, double-buffered swizzled LDS K/V^T, swapped QK^T, in-register
// P -> PV (16x16x16), defer-rescale (T13). 1024 blocks, heavy-first.
// Q pre-scaled by D^-0.5*log2e; softmax in exp2 domain.
// ---------------------------------------------------------------------------
__global__ __launch_bounds__(256) void flash_mfma3(const bf16* __restrict__ QKV,
                                                   const bf16* __restrict__ Vt,
                                                   bf16* __restrict__ Ab) {
    __shared__ __align__(16) bf16 Ks[2][4096];
    __shared__ __align__(16) bf16 Vs[2][4096];
    const int tid = threadIdx.x, lane = tid & 63, wid = tid >> 6;
    const int l16 = lane & 15, lg = lane >> 4;
    const int bid = blockIdx.x;                 // 1024 = 32 qslots x 32 bh
    const int bh = bid & 31;                    // bid%8 = bh%8 -> KV pinned per XCD
    const int qt = 31 - (bid >> 5);             // heavy-first
    const int h = bh & (HH - 1), b = bh >> 4;
    const int wq0 = qt * 64 + wid * 16;
    const int nkt = qt + 1;

    const bf16* Kbase = QKV + (size_t)b * NN * QKVN + CC + h * DD;  // + k*QKVN
    const bf16* Vbase = Vt + (size_t)(b * HH + h) * DD * NN;        // + d*NN + k

    // Q fragments: rows wq0 + l16, two K=32 chunks
    short8 qf[2];
    #pragma unroll
    for (int ch = 0; ch < 2; ++ch)
        qf[ch] = *(const short8*)&QKV[(size_t)(b * NN + wq0 + l16) * QKVN
                                      + h * DD + ch * 32 + lg * 8];

    f32x4 o[4];
    #pragma unroll
    for (int dn = 0; dn < 4; ++dn) o[dn] = {0.f, 0.f, 0.f, 0.f};
    float mx = -1e30f, ls = 0.f;

    auto stage = [&](int kt, int bufi) {
        const int k0s = kt * 64;
        #pragma unroll
        for (int ii = 0; ii < 2; ++ii) {
            const int issue = wid * 2 + ii;
            const int a = issue * 1024 + lane * 16;
            const int r = a >> 7;
            const int cb = (a & 127) ^ ((r & 7) << 4);   // pre-swizzled source
            glds16(Kbase + (size_t)(k0s + r) * QKVN + (cb >> 1), (char*)&Ks[bufi][0] + issue * 1024);
            glds16(Vbase + (size_t)r * NN + k0s + (cb >> 1),     (char*)&Vs[bufi][0] + issue * 1024);
        }
    };

    stage(0, 0);
    __syncthreads();

    for (int kt = 0; kt < nkt; ++kt) {
        const int k0 = kt * 64;
        const int cur = kt & 1;
        if (kt + 1 < nkt) stage(kt + 1, cur ^ 1);

        // ---- S^T = K Q^T : k = kc*16 + lg*4 + r (rows), q = wq0 + l16 (cols) ----
        f32x4 st[4];
        #pragma unroll
        for (int kc = 0; kc < 4; ++kc) st[kc] = {0.f, 0.f, 0.f, 0.f};
        __builtin_amdgcn_s_setprio(1);
        #pragma unroll
        for (int kc = 0; kc < 4; ++kc) {
            const int row = kc * 16 + l16;
            const char* rb = (const char*)&Ks[cur][0] + row * 128;
            const int sw = (row & 7) << 4;
            short8 kf0 = *(const short8*)(rb + ((lg * 16) ^ sw));
            short8 kf1 = *(const short8*)(rb + ((64 + lg * 16) ^ sw));
            st[kc] = __builtin_amdgcn_mfma_f32_16x16x32_bf16(kf0, qf[0], st[kc], 0, 0, 0);
            st[kc] = __builtin_amdgcn_mfma_f32_16x16x32_bf16(kf1, qf[1], st[kc], 0, 0, 0);
        }
        __builtin_amdgcn_s_setprio(0);

        if (kt == qt) {                    // diagonal tile: causal mask
            #pragma unroll
            for (int kc = 0; kc < 4; ++kc)
                #pragma unroll
                for (int r = 0; r < 4; ++r)
                    if (k0 + kc * 16 + lg * 4 + r > wq0 + l16) st[kc][r] = -1e30f;
        }

        // ---- online softmax with defer-rescale ----
        float rm = fmaxf(fmaxf(st[0][0], st[0][1]), fmaxf(st[0][2], st[0][3]));
        #pragma unroll
        for (int kc = 1; kc < 4; ++kc)
            rm = fmaxf(rm, fmaxf(fmaxf(st[kc][0], st[kc][1]), fmaxf(st[kc][2], st[kc][3])));
        rm = fmaxf(rm, __shfl_xor(rm, 16, 64));
        rm = fmaxf(rm, __shfl_xor(rm, 32, 64));
        if (__any(rm > mx + 8.0f)) {       // rescale path (log2 domain, THR=8)
            const float mn = fmaxf(mx, rm);
            const float sc = exp2f(mx - mn);
            ls *= sc;
            #pragma unroll
            for (int dn = 0; dn < 4; ++dn) {
                o[dn][0] *= sc; o[dn][1] *= sc; o[dn][2] *= sc; o[dn][3] *= sc;
            }
            mx = mn;
        }
        float rs = 0.f;
        #pragma unroll
        for (int kc = 0; kc < 4; ++kc)
            #pragma unroll
            for (int r = 0; r < 4; ++r) {
                const float p = exp2f(st[kc][r] - mx);
                st[kc][r] = p; rs += p;
            }
        rs += __shfl_xor(rs, 16, 64);
        rs += __shfl_xor(rs, 32, 64);
        ls += rs;

        // ---- O^T += V^T P^T (16x16x16, k = lg*4+e matches S^T rows) ----
        __builtin_amdgcn_s_setprio(1);
        #pragma unroll
        for (int kc = 0; kc < 4; ++kc) {
            short4v pf;
            pf[0] = pkbf(st[kc][0]); pf[1] = pkbf(st[kc][1]);
            pf[2] = pkbf(st[kc][2]); pf[3] = pkbf(st[kc][3]);
            #pragma unroll
            for (int dn = 0; dn < 4; ++dn) {
                const int row = dn * 16 + l16;
                short4v vf = *(const short4v*)((const char*)&Vs[cur][0] + row * 128
                                               + ((kc * 32 + lg * 8) ^ ((row & 7) << 4)));
                o[dn] = __builtin_amdgcn_mfma_f32_16x16x16bf16_1k(vf, pf, o[dn], 0, 0, 0);
            }
        }
        __builtin_amdgcn_s_setprio(0);

        __syncthreads();      // drains staging vmcnt; next tile ready
    }

    // ---- epilogue: O^T[d][q]/l -> Ab[q][d], 8B stores ----
    const float inv = 1.f / ls;
    const size_t rowb = (size_t)(b * NN + wq0 + l16) * CC + h * DD;
    #pragma unroll
    for (int dn = 0; dn < 4; ++dn) {
        short4v s4;
        s4[0] = pkbf(o[dn][0] * inv); s4[1] = pkbf(o[dn][1] * inv);
        s4[2] = pkbf(o[dn][2] * inv); s4[3] = pkbf(o[dn][3] * inv);
        *(short4v*)&Ab[rowb + dn * 16 + lg * 4] = s4;
    }
}

// ---------------------------------------------------------------------------
extern "C" void kernel_launch(void* const* d_in, const int* in_sizes, int n_in,
                              void* d_out, int out_size, void* d_ws, size_t ws_size,
                              hipStream_t stream) {
    const float* hs   = (const float*)d_in[0];
    const float* cosp = (const float*)d_in[1];
    const float* sinp = (const float*)d_in[2];
    const float* Wq   = (const float*)d_in[3];
    const float* Wk   = (const float*)d_in[4];
    const float* Wv   = (const float*)d_in[5];
    const float* Wo   = (const float*)d_in[6];
    float* out = (float*)d_out;

    char* ws = (char*)d_ws;
    bf16* hsb   = (bf16*)(ws);                    //  8 MB [4096][1024]
    bf16* Wtqkv = (bf16*)(ws + (8  << 20));       //  6 MB [3072][1024]
    bf16* Wto   = (bf16*)(ws + (14 << 20));       //  2 MB [1024][1024]
    bf16* QKV   = (bf16*)(ws + (16 << 20));       // 24 MB [4096][3072] (q,k cols used)
    bf16* Vtb   = (bf16*)(ws + (40 << 20));       //  8 MB [2][16][64][2048]
    bf16* Abuf  = hsb;                            // alias: hs consumed by QKV GEMM

    convert_f32_bf16<<<MM * CC / 1024, 256, 0, stream>>>(hs, hsb);

    transpose4<<<dim3(32, 32, 4), dim3(32, 8), 0, stream>>>(Wq, Wk, Wv, Wo, Wtqkv, Wto);

    gemm2<QKVN, 1><<<dim3(QKVN / 128, MM / 128), 256, 0, stream>>>(
        hsb, Wtqkv, QKV, cosp, sinp, Vtb);

    flash_mfma3<<<1024, 256, 0, stream>>>(QKV, Vtb, Abuf);

    gemm2<CC, 2><<<dim3(CC / 128, MM / 128), 256, 0, stream>>>(
        Abuf, Wto, out, nullptr, nullptr, nullptr);
}

// Round 5
// 133.403 us; speedup vs baseline: 8.8811x; 1.0430x over previous
//
#include <hip/hip_runtime.h>
#include <hip/hip_bf16.h>

typedef __hip_bfloat16 bf16;
typedef __attribute__((ext_vector_type(8))) short short8;
typedef __attribute__((ext_vector_type(4))) short short4v;
typedef __attribute__((ext_vector_type(4))) float f32x4;

#define BB 2
#define NN 2048
#define CC 1024
#define HH 16
#define DD 64
#define MM (BB*NN)     // 4096
#define QKVN 3072
#define LOG2E 1.44269504088896340736f

__device__ __forceinline__ void glds16(const void* g, void* l) {
    __builtin_amdgcn_global_load_lds((const __attribute__((address_space(1))) void*)g,
                                     (__attribute__((address_space(3))) void*)l, 16, 0, 0);
}
__device__ __forceinline__ short pkbf(float x) { bf16 t = (bf16)x; return *(short*)&t; }

// ---------------------------------------------------------------------------
__global__ __launch_bounds__(256) void convert_f32_bf16(const float* __restrict__ in,
                                                        bf16* __restrict__ out) {
    int i = blockIdx.x * 256 + threadIdx.x;
    float4 v = ((const float4*)in)[i];
    short4v s;
    s.x = pkbf(v.x); s.y = pkbf(v.y); s.z = pkbf(v.z); s.w = pkbf(v.w);
    *((short4v*)out + i) = s;
}

// Transpose fp32 W[K][N] -> bf16 Wt[N][K]; z in 0..3 selects Wq,Wk,Wv,Wo
__global__ __launch_bounds__(256) void transpose4(const float* __restrict__ W0,
                                                  const float* __restrict__ W1,
                                                  const float* __restrict__ W2,
                                                  const float* __restrict__ W3,
                                                  bf16* __restrict__ Wtqkv,
                                                  bf16* __restrict__ Wto) {
    __shared__ float t[32][33];
    const int z = blockIdx.z;
    const float* W = z == 0 ? W0 : (z == 1 ? W1 : (z == 2 ? W2 : W3));
    bf16* dst = z < 3 ? Wtqkv + (size_t)z * CC * CC : Wto;
    const int tx = threadIdx.x, ty = threadIdx.y;
    const int x0 = blockIdx.x * 32, y0 = blockIdx.y * 32;
    #pragma unroll
    for (int i = 0; i < 4; ++i)
        t[ty + i * 8][tx] = W[(size_t)(y0 + ty + i * 8) * CC + x0 + tx];
    __syncthreads();
    #pragma unroll
    for (int i = 0; i < 4; ++i)
        dst[(size_t)(x0 + ty + i * 8) * CC + y0 + tx] = (bf16)t[tx][ty + i * 8];
}

// ---------------------------------------------------------------------------
// bf16 MFMA GEMM, double-buffered 2-phase (T3 minimal recipe):
//   stage(t+1) issued BEFORE compute(t); one barrier per K-step.
// MODE 1: QKV epilogue (RoPE+log2e on q/k cols; V written transposed to VtOut)
// MODE 2: fp32 output (out-projection)
// ---------------------------------------------------------------------------
template<int Nn, int MODE>
__global__ __launch_bounds__(256) void gemm3(const bf16* __restrict__ A,
                                             const bf16* __restrict__ Bt,
                                             void* __restrict__ Cout,
                                             const float* __restrict__ cosp,
                                             const float* __restrict__ sinp,
                                             bf16* __restrict__ VtOut) {
    __shared__ __align__(16) bf16 As[2][128 * 32];
    __shared__ __align__(16) bf16 Bs[2][128 * 32];
    const int tid = threadIdx.x, lane = tid & 63, wid = tid >> 6;
    const int wr = wid >> 1, wc = wid & 1, l16 = lane & 15, lg = lane >> 4;
    const int n0 = blockIdx.x * 128, m0 = blockIdx.y * 128;

    f32x4 acc[4][4];
    #pragma unroll
    for (int i = 0; i < 4; ++i)
        #pragma unroll
        for (int j = 0; j < 4; ++j) acc[i][j] = {0.f, 0.f, 0.f, 0.f};

    // per-thread staging coords (row r, 16B chunk cb within the 64B row)
    const int issue0 = wid * 2;
    const int sr0 = (issue0 * 1024 + lane * 16) >> 6;
    const int sc0 = ((issue0 * 1024 + lane * 16) & 63) >> 1;
    const int sr1 = ((issue0 + 1) * 1024 + lane * 16) >> 6;
    const int sc1 = (((issue0 + 1) * 1024 + lane * 16) & 63) >> 1;

    auto stage = [&](int k0, int bufi) {
        glds16(&A [(size_t)(m0 + sr0) * 1024 + k0 + sc0], (char*)&As[bufi][0] + issue0 * 1024);
        glds16(&Bt[(size_t)(n0 + sr0) * 1024 + k0 + sc0], (char*)&Bs[bufi][0] + issue0 * 1024);
        glds16(&A [(size_t)(m0 + sr1) * 1024 + k0 + sc1], (char*)&As[bufi][0] + (issue0 + 1) * 1024);
        glds16(&Bt[(size_t)(n0 + sr1) * 1024 + k0 + sc1], (char*)&Bs[bufi][0] + (issue0 + 1) * 1024);
    };

    stage(0, 0);
    for (int t = 0; t < 32; ++t) {
        const int cur = t & 1;
        __syncthreads();                     // drains stage(t) vmcnt; prev reads done
        if (t + 1 < 32) stage((t + 1) * 32, cur ^ 1);
        short8 af[4], bfr[4];
        #pragma unroll
        for (int i = 0; i < 4; ++i) af[i]  = *(const short8*)((char*)&As[cur][0] + (wr * 64 + i * 16 + l16) * 64 + lg * 16);
        #pragma unroll
        for (int j = 0; j < 4; ++j) bfr[j] = *(const short8*)((char*)&Bs[cur][0] + (wc * 64 + j * 16 + l16) * 64 + lg * 16);
        #pragma unroll
        for (int i = 0; i < 4; ++i)
            #pragma unroll
            for (int j = 0; j < 4; ++j)
                acc[i][j] = __builtin_amdgcn_mfma_f32_16x16x32_bf16(af[i], bfr[j], acc[i][j], 0, 0, 0);
    }

    if (MODE == 1 && n0 >= 2 * CC) {
        // V region: write transposed Vt[b][h][d][n], 8B stores
        #pragma unroll
        for (int i = 0; i < 4; ++i) {
            const int row0 = m0 + wr * 64 + i * 16 + lg * 4;
            const int bb = row0 >> 11, nn_ = row0 & (NN - 1);
            #pragma unroll
            for (int j = 0; j < 4; ++j) {
                const int col = n0 - 2 * CC + wc * 64 + j * 16 + l16;   // 0..1023
                const int hh = col >> 6, d = col & 63;
                short4v s4;
                #pragma unroll
                for (int r = 0; r < 4; ++r) s4[r] = pkbf(acc[i][j][r]);
                *(short4v*)&VtOut[((size_t)(bb * HH + hh) * DD + d) * NN + nn_] = s4;
            }
        }
    } else if (MODE == 1) {
        // q/k region: RoPE; q additionally scaled by D^-0.5 * log2(e).
        // cos[d] == cos[d+32] (emb = concat(freqs,freqs)) -> one c,s per pair.
        const float qs = (n0 < CC) ? 0.125f * LOG2E : 1.0f;
        bf16* Cb = (bf16*)Cout;
        #pragma unroll
        for (int i = 0; i < 4; ++i)
            #pragma unroll
            for (int r = 0; r < 4; ++r) {
                const int row = m0 + wr * 64 + i * 16 + lg * 4 + r;
                #pragma unroll
                for (int j = 0; j < 2; ++j) {
                    const int d = j * 16 + l16;          // < 32
                    const float cv = cosp[(size_t)row * DD + d];
                    const float sv = sinp[(size_t)row * DD + d];
                    const float x1 = acc[i][j][r];       // value at d
                    const float x2 = acc[i][j + 2][r];   // value at d+32
                    const size_t cbase = (size_t)row * QKVN + n0 + wc * 64 + j * 16 + l16;
                    Cb[cbase]      = (bf16)((x1 * cv - x2 * sv) * qs);
                    Cb[cbase + 32] = (bf16)((x2 * cv + x1 * sv) * qs);
                }
            }
    } else {
        float* Cf = (float*)Cout;
        #pragma unroll
        for (int i = 0; i < 4; ++i)
            #pragma unroll
            for (int r = 0; r < 4; ++r) {
                const int row = m0 + wr * 64 + i * 16 + lg * 4 + r;
                #pragma unroll
                for (int j = 0; j < 4; ++j)
                    Cf[(size_t)row * Nn + n0 + wc * 64 + j * 16 + l16] = acc[i][j][r];
            }
    }
}

// ---------------------------------------------------------------------------
// Flash attention v3 (unchanged from round 4): one 64-row q-tile per block,
// 4 waves x 16 q-rows, KVBLK=64, double-buffered swizzled LDS K/V^T, swapped
// QK^T, in-register P -> PV (16x16x16), defer-rescale. Heavy-first dispatch.
// ---------------------------------------------------------------------------
__global__ __launch_bounds__(256) void flash_mfma3(const bf16* __restrict__ QKV,
                                                   const bf16* __restrict__ Vt,
                                                   bf16* __restrict__ Ab) {
    __shared__ __align__(16) bf16 Ks[2][4096];
    __shared__ __align__(16) bf16 Vs[2][4096];
    const int tid = threadIdx.x, lane = tid & 63, wid = tid >> 6;
    const int l16 = lane & 15, lg = lane >> 4;
    const int bid = blockIdx.x;                 // 1024 = 32 qslots x 32 bh
    const int bh = bid & 31;                    // bid%8 = bh%8 -> KV pinned per XCD
    const int qt = 31 - (bid >> 5);             // heavy-first
    const int h = bh & (HH - 1), b = bh >> 4;
    const int wq0 = qt * 64 + wid * 16;
    const int nkt = qt + 1;

    const bf16* Kbase = QKV + (size_t)b * NN * QKVN + CC + h * DD;  // + k*QKVN
    const bf16* Vbase = Vt + (size_t)(b * HH + h) * DD * NN;        // + d*NN + k

    short8 qf[2];
    #pragma unroll
    for (int ch = 0; ch < 2; ++ch)
        qf[ch] = *(const short8*)&QKV[(size_t)(b * NN + wq0 + l16) * QKVN
                                      + h * DD + ch * 32 + lg * 8];

    f32x4 o[4];
    #pragma unroll
    for (int dn = 0; dn < 4; ++dn) o[dn] = {0.f, 0.f, 0.f, 0.f};
    float mx = -1e30f, ls = 0.f;

    auto stage = [&](int kt, int bufi) {
        const int k0s = kt * 64;
        #pragma unroll
        for (int ii = 0; ii < 2; ++ii) {
            const int issue = wid * 2 + ii;
            const int a = issue * 1024 + lane * 16;
            const int r = a >> 7;
            const int cb = (a & 127) ^ ((r & 7) << 4);   // pre-swizzled source
            glds16(Kbase + (size_t)(k0s + r) * QKVN + (cb >> 1), (char*)&Ks[bufi][0] + issue * 1024);
            glds16(Vbase + (size_t)r * NN + k0s + (cb >> 1),     (char*)&Vs[bufi][0] + issue * 1024);
        }
    };

    stage(0, 0);
    __syncthreads();

    for (int kt = 0; kt < nkt; ++kt) {
        const int k0 = kt * 64;
        const int cur = kt & 1;
        if (kt + 1 < nkt) stage(kt + 1, cur ^ 1);

        f32x4 st[4];
        #pragma unroll
        for (int kc = 0; kc < 4; ++kc) st[kc] = {0.f, 0.f, 0.f, 0.f};
        __builtin_amdgcn_s_setprio(1);
        #pragma unroll
        for (int kc = 0; kc < 4; ++kc) {
            const int row = kc * 16 + l16;
            const char* rb = (const char*)&Ks[cur][0] + row * 128;
            const int sw = (row & 7) << 4;
            short8 kf0 = *(const short8*)(rb + ((lg * 16) ^ sw));
            short8 kf1 = *(const short8*)(rb + ((64 + lg * 16) ^ sw));
            st[kc] = __builtin_amdgcn_mfma_f32_16x16x32_bf16(kf0, qf[0], st[kc], 0, 0, 0);
            st[kc] = __builtin_amdgcn_mfma_f32_16x16x32_bf16(kf1, qf[1], st[kc], 0, 0, 0);
        }
        __builtin_amdgcn_s_setprio(0);

        if (kt == qt) {
            #pragma unroll
            for (int kc = 0; kc < 4; ++kc)
                #pragma unroll
                for (int r = 0; r < 4; ++r)
                    if (k0 + kc * 16 + lg * 4 + r > wq0 + l16) st[kc][r] = -1e30f;
        }

        float rm = fmaxf(fmaxf(st[0][0], st[0][1]), fmaxf(st[0][2], st[0][3]));
        #pragma unroll
        for (int kc = 1; kc < 4; ++kc)
            rm = fmaxf(rm, fmaxf(fmaxf(st[kc][0], st[kc][1]), fmaxf(st[kc][2], st[kc][3])));
        rm = fmaxf(rm, __shfl_xor(rm, 16, 64));
        rm = fmaxf(rm, __shfl_xor(rm, 32, 64));
        if (__any(rm > mx + 8.0f)) {
            const float mn = fmaxf(mx, rm);
            const float sc = exp2f(mx - mn);
            ls *= sc;
            #pragma unroll
            for (int dn = 0; dn < 4; ++dn) {
                o[dn][0] *= sc; o[dn][1] *= sc; o[dn][2] *= sc; o[dn][3] *= sc;
            }
            mx = mn;
        }
        float rs = 0.f;
        #pragma unroll
        for (int kc = 0; kc < 4; ++kc)
            #pragma unroll
            for (int r = 0; r < 4; ++r) {
                const float p = exp2f(st[kc][r] - mx);
                st[kc][r] = p; rs += p;
            }
        rs += __shfl_xor(rs, 16, 64);
        rs += __shfl_xor(rs, 32, 64);
        ls += rs;

        __builtin_amdgcn_s_setprio(1);
        #pragma unroll
        for (int kc = 0; kc < 4; ++kc) {
            short4v pf;
            pf[0] = pkbf(st[kc][0]); pf[1] = pkbf(st[kc][1]);
            pf[2] = pkbf(st[kc][2]); pf[3] = pkbf(st[kc][3]);
            #pragma unroll
            for (int dn = 0; dn < 4; ++dn) {
                const int row = dn * 16 + l16;
                short4v vf = *(const short4v*)((const char*)&Vs[cur][0] + row * 128
                                               + ((kc * 32 + lg * 8) ^ ((row & 7) << 4)));
                o[dn] = __builtin_amdgcn_mfma_f32_16x16x16bf16_1k(vf, pf, o[dn], 0, 0, 0);
            }
        }
        __builtin_amdgcn_s_setprio(0);

        __syncthreads();
    }

    const float inv = 1.f / ls;
    const size_t rowb = (size_t)(b * NN + wq0 + l16) * CC + h * DD;
    #pragma unroll
    for (int dn = 0; dn < 4; ++dn) {
        short4v s4;
        s4[0] = pkbf(o[dn][0] * inv); s4[1] = pkbf(o[dn][1] * inv);
        s4[2] = pkbf(o[dn][2] * inv); s4[3] = pkbf(o[dn][3] * inv);
        *(short4v*)&Ab[rowb + dn * 16 + lg * 4] = s4;
    }
}

// ---------------------------------------------------------------------------
extern "C" void kernel_launch(void* const* d_in, const int* in_sizes, int n_in,
                              void* d_out, int out_size, void* d_ws, size_t ws_size,
                              hipStream_t stream) {
    const float* hs   = (const float*)d_in[0];
    const float* cosp = (const float*)d_in[1];
    const float* sinp = (const float*)d_in[2];
    const float* Wq   = (const float*)d_in[3];
    const float* Wk   = (const float*)d_in[4];
    const float* Wv   = (const float*)d_in[5];
    const float* Wo   = (const float*)d_in[6];
    float* out = (float*)d_out;

    char* ws = (char*)d_ws;
    bf16* hsb   = (bf16*)(ws);                    //  8 MB [4096][1024]
    bf16* Wtqkv = (bf16*)(ws + (8  << 20));       //  6 MB [3072][1024]
    bf16* Wto   = (bf16*)(ws + (14 << 20));       //  2 MB [1024][1024]
    bf16* QKV   = (bf16*)(ws + (16 << 20));       // 24 MB [4096][3072] (q,k cols used)
    bf16* Vtb   = (bf16*)(ws + (40 << 20));       //  8 MB [2][16][64][2048]
    bf16* Abuf  = hsb;                            // alias: hs consumed by QKV GEMM

    convert_f32_bf16<<<MM * CC / 1024, 256, 0, stream>>>(hs, hsb);

    transpose4<<<dim3(32, 32, 4), dim3(32, 8), 0, stream>>>(Wq, Wk, Wv, Wo, Wtqkv, Wto);

    gemm3<QKVN, 1><<<dim3(QKVN / 128, MM / 128), 256, 0, stream>>>(
        hsb, Wtqkv, QKV, cosp, sinp, Vtb);

    flash_mfma3<<<1024, 256, 0, stream>>>(QKV, Vtb, Abuf);

    gemm3<CC, 2><<<dim3(CC / 128, MM / 128), 256, 0, stream>>>(
        Abuf, Wto, out, nullptr, nullptr, nullptr);
}

// Round 7
// 129.311 us; speedup vs baseline: 9.1622x; 1.0316x over previous
//
#include <hip/hip_runtime.h>
#include <hip/hip_bf16.h>

typedef __hip_bfloat16 bf16;
typedef __attribute__((ext_vector_type(8))) short short8;
typedef __attribute__((ext_vector_type(4))) short short4v;
typedef __attribute__((ext_vector_type(4))) float f32x4;

#define BB 2
#define NN 2048
#define CC 1024
#define HH 16
#define DD 64
#define MM (BB*NN)     // 4096
#define QKVN 3072
#define LOG2E 1.44269504088896340736f

__device__ __forceinline__ void glds16(const void* g, void* l) {
    __builtin_amdgcn_global_load_lds((const __attribute__((address_space(1))) void*)g,
                                     (__attribute__((address_space(3))) void*)l, 16, 0, 0);
}
__device__ __forceinline__ short pkbf(float x) { bf16 t = (bf16)x; return *(short*)&t; }
__device__ __forceinline__ float b2f(short s) {
    return __uint_as_float(((unsigned)(unsigned short)s) << 16);
}

// ---------------------------------------------------------------------------
__global__ __launch_bounds__(256) void convert_f32_bf16(const float* __restrict__ in,
                                                        bf16* __restrict__ out) {
    int i = blockIdx.x * 256 + threadIdx.x;
    float4 v = ((const float4*)in)[i];
    short4v s;
    s.x = pkbf(v.x); s.y = pkbf(v.y); s.z = pkbf(v.z); s.w = pkbf(v.w);
    *((short4v*)out + i) = s;
}

// Transpose fp32 W[K][N] -> bf16 Wt[N][K]; z in 0..3 selects Wq,Wk,Wv,Wo
__global__ __launch_bounds__(256) void transpose4(const float* __restrict__ W0,
                                                  const float* __restrict__ W1,
                                                  const float* __restrict__ W2,
                                                  const float* __restrict__ W3,
                                                  bf16* __restrict__ Wtqkv,
                                                  bf16* __restrict__ Wto) {
    __shared__ float t[32][33];
    const int z = blockIdx.z;
    const float* W = z == 0 ? W0 : (z == 1 ? W1 : (z == 2 ? W2 : W3));
    bf16* dst = z < 3 ? Wtqkv + (size_t)z * CC * CC : Wto;
    const int tx = threadIdx.x, ty = threadIdx.y;
    const int x0 = blockIdx.x * 32, y0 = blockIdx.y * 32;
    #pragma unroll
    for (int i = 0; i < 4; ++i)
        t[ty + i * 8][tx] = W[(size_t)(y0 + ty + i * 8) * CC + x0 + tx];
    __syncthreads();
    #pragma unroll
    for (int i = 0; i < 4; ++i)
        dst[(size_t)(x0 + ty + i * 8) * CC + y0 + tx] = (bf16)t[tx][ty + i * 8];
}

// ---------------------------------------------------------------------------
// bf16 MFMA GEMM, double-buffered 2-phase.
// MODE 1: QKV epilogue (RoPE+log2e on q/k cols; V written transposed to VtOut)
// MODE 2: fp32 output (out-projection)
// ---------------------------------------------------------------------------
template<int Nn, int MODE>
__global__ __launch_bounds__(256) void gemm3(const bf16* __restrict__ A,
                                             const bf16* __restrict__ Bt,
                                             void* __restrict__ Cout,
                                             const float* __restrict__ cosp,
                                             const float* __restrict__ sinp,
                                             bf16* __restrict__ VtOut) {
    __shared__ __align__(16) bf16 As[2][128 * 32];
    __shared__ __align__(16) bf16 Bs[2][128 * 32];
    const int tid = threadIdx.x, lane = tid & 63, wid = tid >> 6;
    const int wr = wid >> 1, wc = wid & 1, l16 = lane & 15, lg = lane >> 4;
    const int n0 = blockIdx.x * 128, m0 = blockIdx.y * 128;

    f32x4 acc[4][4];
    #pragma unroll
    for (int i = 0; i < 4; ++i)
        #pragma unroll
        for (int j = 0; j < 4; ++j) acc[i][j] = {0.f, 0.f, 0.f, 0.f};

    const int issue0 = wid * 2;
    const int sr0 = (issue0 * 1024 + lane * 16) >> 6;
    const int sc0 = ((issue0 * 1024 + lane * 16) & 63) >> 1;
    const int sr1 = ((issue0 + 1) * 1024 + lane * 16) >> 6;
    const int sc1 = (((issue0 + 1) * 1024 + lane * 16) & 63) >> 1;

    auto stage = [&](int k0, int bufi) {
        glds16(&A [(size_t)(m0 + sr0) * 1024 + k0 + sc0], (char*)&As[bufi][0] + issue0 * 1024);
        glds16(&Bt[(size_t)(n0 + sr0) * 1024 + k0 + sc0], (char*)&Bs[bufi][0] + issue0 * 1024);
        glds16(&A [(size_t)(m0 + sr1) * 1024 + k0 + sc1], (char*)&As[bufi][0] + (issue0 + 1) * 1024);
        glds16(&Bt[(size_t)(n0 + sr1) * 1024 + k0 + sc1], (char*)&Bs[bufi][0] + (issue0 + 1) * 1024);
    };

    stage(0, 0);
    for (int t = 0; t < 32; ++t) {
        const int cur = t & 1;
        __syncthreads();
        if (t + 1 < 32) stage((t + 1) * 32, cur ^ 1);
        short8 af[4], bfr[4];
        #pragma unroll
        for (int i = 0; i < 4; ++i) af[i]  = *(const short8*)((char*)&As[cur][0] + (wr * 64 + i * 16 + l16) * 64 + lg * 16);
        #pragma unroll
        for (int j = 0; j < 4; ++j) bfr[j] = *(const short8*)((char*)&Bs[cur][0] + (wc * 64 + j * 16 + l16) * 64 + lg * 16);
        #pragma unroll
        for (int i = 0; i < 4; ++i)
            #pragma unroll
            for (int j = 0; j < 4; ++j)
                acc[i][j] = __builtin_amdgcn_mfma_f32_16x16x32_bf16(af[i], bfr[j], acc[i][j], 0, 0, 0);
    }

    if (MODE == 1 && n0 >= 2 * CC) {
        #pragma unroll
        for (int i = 0; i < 4; ++i) {
            const int row0 = m0 + wr * 64 + i * 16 + lg * 4;
            const int bb = row0 >> 11, nn_ = row0 & (NN - 1);
            #pragma unroll
            for (int j = 0; j < 4; ++j) {
                const int col = n0 - 2 * CC + wc * 64 + j * 16 + l16;
                const int hh = col >> 6, d = col & 63;
                short4v s4;
                #pragma unroll
                for (int r = 0; r < 4; ++r) s4[r] = pkbf(acc[i][j][r]);
                *(short4v*)&VtOut[((size_t)(bb * HH + hh) * DD + d) * NN + nn_] = s4;
            }
        }
    } else if (MODE == 1) {
        const float qs = (n0 < CC) ? 0.125f * LOG2E : 1.0f;
        bf16* Cb = (bf16*)Cout;
        #pragma unroll
        for (int i = 0; i < 4; ++i)
            #pragma unroll
            for (int r = 0; r < 4; ++r) {
                const int row = m0 + wr * 64 + i * 16 + lg * 4 + r;
                #pragma unroll
                for (int j = 0; j < 2; ++j) {
                    const int d = j * 16 + l16;          // < 32
                    const float cv = cosp[(size_t)row * DD + d];
                    const float sv = sinp[(size_t)row * DD + d];
                    const float x1 = acc[i][j][r];
                    const float x2 = acc[i][j + 2][r];
                    const size_t cbase = (size_t)row * QKVN + n0 + wc * 64 + j * 16 + l16;
                    Cb[cbase]      = (bf16)((x1 * cv - x2 * sv) * qs);
                    Cb[cbase + 32] = (bf16)((x2 * cv + x1 * sv) * qs);
                }
            }
    } else {
        float* Cf = (float*)Cout;
        #pragma unroll
        for (int i = 0; i < 4; ++i)
            #pragma unroll
            for (int r = 0; r < 4; ++r) {
                const int row = m0 + wr * 64 + i * 16 + lg * 4 + r;
                #pragma unroll
                for (int j = 0; j < 4; ++j)
                    Cf[(size_t)row * Nn + n0 + wc * 64 + j * 16 + l16] = acc[i][j][r];
            }
    }
}

// ---------------------------------------------------------------------------
// Flash attention v4: split-KV (flash-decoding). 2048 blocks = 64 slots x 32 bh.
// cnt==0 blocks fall through and write ZERO partials (PartB must be written
// every call: it aliases d_out, which holds stale fp32 garbage across graph
// replays -> NaN*0 in merge otherwise).
// ---------------------------------------------------------------------------
__global__ __launch_bounds__(256) void flash_mfma4(const bf16* __restrict__ QKV,
                                                   const bf16* __restrict__ Vt,
                                                   bf16* __restrict__ PartA,
                                                   bf16* __restrict__ PartB,
                                                   float2* __restrict__ Mlb) {
    __shared__ __align__(16) bf16 Ks[2][4096];
    __shared__ __align__(16) bf16 Vs[2][4096];
    const int tid = threadIdx.x, lane = tid & 63, wid = tid >> 6;
    const int l16 = lane & 15, lg = lane >> 4;
    const int bid = blockIdx.x;                 // 2048 = 64 slots x 32 bh
    const int bh = bid & 31;                    // bid%8 spreads bh across XCDs
    const int slot = bid >> 5;                  // 0..63, heavy-first
    const int qt = 31 - (slot >> 1);
    const int half = slot & 1;
    const int h = bh & (HH - 1), b = bh >> 4;
    const int wq0 = qt * 64 + wid * 16;
    const int nkt = qt + 1;
    const int hf = (nkt + 1) >> 1;
    const int t0 = half ? hf : 0;
    const int cnt = (half ? nkt : hf) - t0;
    const int grow = b * NN + wq0 + l16;        // global q-row of lane's column

    const bf16* Kbase = QKV + (size_t)b * NN * QKVN + CC + h * DD;  // + k*QKVN
    const bf16* Vbase = Vt + (size_t)(b * HH + h) * DD * NN;        // + d*NN + k

    // Q fragments: rows wq0 + l16, two K=32 chunks
    short8 qf[2];
    #pragma unroll
    for (int ch = 0; ch < 2; ++ch)
        qf[ch] = *(const short8*)&QKV[(size_t)grow * QKVN + h * DD + ch * 32 + lg * 8];

    f32x4 o[4];
    #pragma unroll
    for (int dn = 0; dn < 4; ++dn) o[dn] = {0.f, 0.f, 0.f, 0.f};
    float mx = -1e30f, ls = 0.f;

    // staging pointers (advance by constants each tile)
    const int a0 = (wid * 2) * 1024 + lane * 16, a1 = a0 + 1024;
    const int r0 = a0 >> 7, c0 = ((a0 & 127) ^ ((r0 & 7) << 4)) >> 1;
    const int r1 = a1 >> 7, c1 = ((a1 & 127) ^ ((r1 & 7) << 4)) >> 1;
    const bf16* kp0 = Kbase + (size_t)(t0 * 64 + r0) * QKVN + c0;
    const bf16* kp1 = Kbase + (size_t)(t0 * 64 + r1) * QKVN + c1;
    const bf16* vp0 = Vbase + (size_t)r0 * NN + t0 * 64 + c0;
    const bf16* vp1 = Vbase + (size_t)r1 * NN + t0 * 64 + c1;
    char* ldsK = (char*)&Ks[0][0] + wid * 2048;
    char* ldsV = (char*)&Vs[0][0] + wid * 2048;

    auto stage = [&](int par) {
        glds16(kp0, ldsK + par * 8192);
        glds16(kp1, ldsK + par * 8192 + 1024);
        glds16(vp0, ldsV + par * 8192);
        glds16(vp1, ldsV + par * 8192 + 1024);
        kp0 += 64 * QKVN; kp1 += 64 * QKVN; vp0 += 64; vp1 += 64;
    };

    if (cnt > 0) stage(0);
    for (int i = 0; i < cnt; ++i) {
        __syncthreads();                 // drains stage(i) vmcnt; buf[(i+1)&1] reads done
        if (i + 1 < cnt) stage((i + 1) & 1);
        const int cur = i & 1;
        const int kt = t0 + i;
        const int k0 = kt * 64;

        // ---- S^T = K Q^T : k rows, q cols ----
        f32x4 st[4];
        #pragma unroll
        for (int kc = 0; kc < 4; ++kc) st[kc] = {0.f, 0.f, 0.f, 0.f};
        __builtin_amdgcn_s_setprio(1);
        #pragma unroll
        for (int kc = 0; kc < 4; ++kc) {
            const int row = kc * 16 + l16;
            const char* rb = (const char*)&Ks[cur][0] + row * 128;
            const int sw = (row & 7) << 4;
            short8 kf0 = *(const short8*)(rb + ((lg * 16) ^ sw));
            short8 kf1 = *(const short8*)(rb + ((64 + lg * 16) ^ sw));
            st[kc] = __builtin_amdgcn_mfma_f32_16x16x32_bf16(kf0, qf[0], st[kc], 0, 0, 0);
            st[kc] = __builtin_amdgcn_mfma_f32_16x16x32_bf16(kf1, qf[1], st[kc], 0, 0, 0);
        }
        __builtin_amdgcn_s_setprio(0);

        if (kt == qt) {                  // diagonal tile: causal mask
            #pragma unroll
            for (int kc = 0; kc < 4; ++kc)
                #pragma unroll
                for (int r = 0; r < 4; ++r)
                    if (k0 + kc * 16 + lg * 4 + r > wq0 + l16) st[kc][r] = -1e30f;
        }

        // ---- online softmax (exp2 domain), defer-rescale ----
        float rm = fmaxf(fmaxf(st[0][0], st[0][1]), fmaxf(st[0][2], st[0][3]));
        #pragma unroll
        for (int kc = 1; kc < 4; ++kc)
            rm = fmaxf(rm, fmaxf(fmaxf(st[kc][0], st[kc][1]), fmaxf(st[kc][2], st[kc][3])));
        rm = fmaxf(rm, __shfl_xor(rm, 16, 64));
        rm = fmaxf(rm, __shfl_xor(rm, 32, 64));
        if (__any(rm > mx + 8.0f)) {
            const float mn = fmaxf(mx, rm);
            const float sc = __builtin_amdgcn_exp2f(mx - mn);
            ls *= sc;
            #pragma unroll
            for (int dn = 0; dn < 4; ++dn) {
                o[dn][0] *= sc; o[dn][1] *= sc; o[dn][2] *= sc; o[dn][3] *= sc;
            }
            mx = mn;
        }
        float rs = 0.f;
        #pragma unroll
        for (int kc = 0; kc < 4; ++kc)
            #pragma unroll
            for (int r = 0; r < 4; ++r) {
                const float p = __builtin_amdgcn_exp2f(st[kc][r] - mx);
                st[kc][r] = p; rs += p;
            }
        rs += __shfl_xor(rs, 16, 64);
        rs += __shfl_xor(rs, 32, 64);
        ls += rs;

        // ---- O^T += V^T P^T ----
        __builtin_amdgcn_s_setprio(1);
        #pragma unroll
        for (int kc = 0; kc < 4; ++kc) {
            short4v pf;
            pf[0] = pkbf(st[kc][0]); pf[1] = pkbf(st[kc][1]);
            pf[2] = pkbf(st[kc][2]); pf[3] = pkbf(st[kc][3]);
            #pragma unroll
            for (int dn = 0; dn < 4; ++dn) {
                const int row = dn * 16 + l16;
                short4v vf = *(const short4v*)((const char*)&Vs[cur][0] + row * 128
                                               + ((kc * 32 + lg * 8) ^ ((row & 7) << 4)));
                o[dn] = __builtin_amdgcn_mfma_f32_16x16x16bf16_1k(vf, pf, o[dn], 0, 0, 0);
            }
        }
        __builtin_amdgcn_s_setprio(0);
    }

    // ---- partial epilogue: UN-normalized O + (m,l); cnt==0 writes zeros ----
    if (lg == 0) Mlb[((size_t)(half * MM) + grow) * HH + h] = make_float2(mx, ls);
    bf16* dst = half ? PartB : PartA;
    const size_t rowb = (size_t)grow * CC + h * DD;
    #pragma unroll
    for (int dn = 0; dn < 4; ++dn) {
        short4v s4;
        s4[0] = pkbf(o[dn][0]); s4[1] = pkbf(o[dn][1]);
        s4[2] = pkbf(o[dn][2]); s4[3] = pkbf(o[dn][3]);
        *(short4v*)&dst[rowb + dn * 16 + lg * 4] = s4;
    }
}

// ---------------------------------------------------------------------------
// Combine the two KV-halves: out = (o0*2^(m0-M) + o1*2^(m1-M)) / (l0*2^(m0-M)+l1*2^(m1-M))
// ---------------------------------------------------------------------------
__global__ __launch_bounds__(256) void merge_halves(const bf16* __restrict__ pa,
                                                    const bf16* __restrict__ pb,
                                                    const float2* __restrict__ ml,
                                                    bf16* __restrict__ outp) {
    const int idx = blockIdx.x * 256 + threadIdx.x;    // 524288 total
    const int row = idx >> 7;
    const int h = (idx & 127) >> 3;
    const float2 a = ml[(size_t)row * HH + h];
    const float2 bb = ml[((size_t)MM + row) * HH + h];
    const float M = fmaxf(a.x, bb.x);
    const float w0 = __builtin_amdgcn_exp2f(a.x - M);
    const float w1 = (bb.y > 0.f) ? __builtin_amdgcn_exp2f(bb.x - M) : 0.f;
    const float inv = 1.f / (a.y * w0 + bb.y * w1);
    const float f0 = w0 * inv, f1 = w1 * inv;
    const size_t off = (size_t)idx * 8;
    short8 va = *(const short8*)(pa + off);
    short8 vb = *(const short8*)(pb + off);
    short8 ov;
    #pragma unroll
    for (int e = 0; e < 8; ++e)
        ov[e] = pkbf(b2f(va[e]) * f0 + b2f(vb[e]) * f1);
    *(short8*)(outp + off) = ov;
}

// ---------------------------------------------------------------------------
extern "C" void kernel_launch(void* const* d_in, const int* in_sizes, int n_in,
                              void* d_out, int out_size, void* d_ws, size_t ws_size,
                              hipStream_t stream) {
    const float* hs   = (const float*)d_in[0];
    const float* cosp = (const float*)d_in[1];
    const float* sinp = (const float*)d_in[2];
    const float* Wq   = (const float*)d_in[3];
    const float* Wk   = (const float*)d_in[4];
    const float* Wv   = (const float*)d_in[5];
    const float* Wo   = (const float*)d_in[6];
    float* out = (float*)d_out;

    char* ws = (char*)d_ws;
    bf16* hsb   = (bf16*)(ws);                    //  8 MB [4096][1024]
    bf16* Wtqkv = (bf16*)(ws + (8  << 20));       //  6 MB [3072][1024]
    bf16* Wto   = (bf16*)(ws + (14 << 20));       //  2 MB [1024][1024]
    bf16* QKV   = (bf16*)(ws + (16 << 20));       // 24 MB [4096][3072] (q,k cols used)
    bf16* Vtb   = (bf16*)(ws + (40 << 20));       //  8 MB [2][16][64][2048]
    bf16* Abuf  = hsb;                            // alias: hs consumed by QKV GEMM
    float2* Mlb = (float2*)Wtqkv;                 // alias: Wtqkv dead after QKV GEMM (1 MB)
    bf16* PartB = (bf16*)out;                     // d_out as scratch until out-GEMM

    convert_f32_bf16<<<MM * CC / 1024, 256, 0, stream>>>(hs, hsb);

    transpose4<<<dim3(32, 32, 4), dim3(32, 8), 0, stream>>>(Wq, Wk, Wv, Wo, Wtqkv, Wto);

    gemm3<QKVN, 1><<<dim3(QKVN / 128, MM / 128), 256, 0, stream>>>(
        hsb, Wtqkv, QKV, cosp, sinp, Vtb);

    flash_mfma4<<<2048, 256, 0, stream>>>(QKV, Vtb, Abuf, PartB, Mlb);

    merge_halves<<<2048, 256, 0, stream>>>(Abuf, PartB, Mlb, Abuf);

    gemm3<CC, 2><<<dim3(CC / 128, MM / 128), 256, 0, stream>>>(
        Abuf, Wto, out, nullptr, nullptr, nullptr);
}

// Round 8
// 127.023 us; speedup vs baseline: 9.3272x; 1.0180x over previous
//
#include <hip/hip_runtime.h>
#include <hip/hip_bf16.h>

typedef __hip_bfloat16 bf16;
typedef __attribute__((ext_vector_type(8))) short short8;
typedef __attribute__((ext_vector_type(4))) short short4v;
typedef __attribute__((ext_vector_type(4))) float f32x4;

#define BB 2
#define NN 2048
#define CC 1024
#define HH 16
#define DD 64
#define MM (BB*NN)     // 4096
#define QKVN 3072
#define LOG2E 1.44269504088896340736f

__device__ __forceinline__ void glds16(const void* g, void* l) {
    __builtin_amdgcn_global_load_lds((const __attribute__((address_space(1))) void*)g,
                                     (__attribute__((address_space(3))) void*)l, 16, 0, 0);
}
__device__ __forceinline__ short pkbf(float x) { bf16 t = (bf16)x; return *(short*)&t; }
__device__ __forceinline__ float b2f(short s) {
    return __uint_as_float(((unsigned)(unsigned short)s) << 16);
}

// ---------------------------------------------------------------------------
__global__ __launch_bounds__(256) void convert_f32_bf16(const float* __restrict__ in,
                                                        bf16* __restrict__ out) {
    int i = blockIdx.x * 256 + threadIdx.x;
    float4 v = ((const float4*)in)[i];
    short4v s;
    s.x = pkbf(v.x); s.y = pkbf(v.y); s.z = pkbf(v.z); s.w = pkbf(v.w);
    *((short4v*)out + i) = s;
}

// Transpose fp32 W[K][N] -> bf16 Wt[N][K]; z in 0..3 selects Wq,Wk,Wv,Wo
__global__ __launch_bounds__(256) void transpose4(const float* __restrict__ W0,
                                                  const float* __restrict__ W1,
                                                  const float* __restrict__ W2,
                                                  const float* __restrict__ W3,
                                                  bf16* __restrict__ Wtqkv,
                                                  bf16* __restrict__ Wto) {
    __shared__ float t[32][33];
    const int z = blockIdx.z;
    const float* W = z == 0 ? W0 : (z == 1 ? W1 : (z == 2 ? W2 : W3));
    bf16* dst = z < 3 ? Wtqkv + (size_t)z * CC * CC : Wto;
    const int tx = threadIdx.x, ty = threadIdx.y;
    const int x0 = blockIdx.x * 32, y0 = blockIdx.y * 32;
    #pragma unroll
    for (int i = 0; i < 4; ++i)
        t[ty + i * 8][tx] = W[(size_t)(y0 + ty + i * 8) * CC + x0 + tx];
    __syncthreads();
    #pragma unroll
    for (int i = 0; i < 4; ++i)
        dst[(size_t)(x0 + ty + i * 8) * CC + y0 + tx] = (bf16)t[tx][ty + i * 8];
}

// ---------------------------------------------------------------------------
// 8-phase 256x256 (BK=64) bf16 MFMA GEMM for the QKV projection (K=1024).
// T2 XOR-swizzled LDS (pre-swizzled global source, swizzled ds_read),
// T3/T4 counted vmcnt(6) at phase-3/7 ends, T5 setprio around MFMA clusters.
// Epilogue: RoPE+log2e on q/k cols; V written transposed to VtOut.
// ---------------------------------------------------------------------------
__global__ __launch_bounds__(512, 2) void gemm8(const bf16* __restrict__ A,
                                                const bf16* __restrict__ Bt,
                                                bf16* __restrict__ Cb,
                                                const float* __restrict__ cosp,
                                                const float* __restrict__ sinp,
                                                bf16* __restrict__ VtOut) {
    __shared__ __align__(16) bf16 As[2][256 * 64];   // 64 KB
    __shared__ __align__(16) bf16 Bs[2][256 * 64];   // 64 KB
    const int tid = threadIdx.x, lane = tid & 63, wid = tid >> 6;
    const int wm = wid >> 2, wn = wid & 3, l16 = lane & 15, lg = lane >> 4;
    const int n0 = blockIdx.x * 256, m0 = blockIdx.y * 256;

    f32x4 acc[8][4];
    #pragma unroll
    for (int i = 0; i < 8; ++i)
        #pragma unroll
        for (int j = 0; j < 4; ++j) acc[i][j] = {0.f, 0.f, 0.f, 0.f};

    // staging: per half-tile (128 rows x 64 cols), 2 glds16/thread, pre-swizzled src
    const int srow = lane >> 3;                                     // 0..7
    const int sce  = (((lane & 7) * 16) ^ ((lane >> 3) << 4)) >> 1; // swizzled elem col
    auto stA = [&](int t, int hf, int bi) {
        #pragma unroll
        for (int j = 0; j < 2; ++j) {
            const int rl = hf * 128 + (wid * 2 + j) * 8;
            glds16(&A[(size_t)(m0 + rl + srow) * 1024 + t * 64 + sce], (void*)&As[bi][rl * 64]);
        }
    };
    auto stB = [&](int t, int hf, int bi) {
        #pragma unroll
        for (int j = 0; j < 2; ++j) {
            const int rl = hf * 128 + (wid * 2 + j) * 8;
            glds16(&Bt[(size_t)(n0 + rl + srow) * 1024 + t * 64 + sce], (void*)&Bs[bi][rl * 64]);
        }
    };

    short8 af[4][2], bfr[4][2];
    const int swz = (l16 & 7) << 4;
    auto rdA = [&](int mh, int bi) {
        #pragma unroll
        for (int f = 0; f < 4; ++f) {
            const char* rb = (const char*)&As[bi][0] + (wm * 128 + (mh * 4 + f) * 16 + l16) * 128;
            af[f][0] = *(const short8*)(rb + ((lg * 16) ^ swz));
            af[f][1] = *(const short8*)(rb + ((64 + lg * 16) ^ swz));
        }
    };
    auto rdB = [&](int nh, int bi) {
        #pragma unroll
        for (int f = 0; f < 2; ++f) {
            const char* rb = (const char*)&Bs[bi][0] + (wn * 64 + (nh * 2 + f) * 16 + l16) * 128;
            bfr[nh * 2 + f][0] = *(const short8*)(rb + ((lg * 16) ^ swz));
            bfr[nh * 2 + f][1] = *(const short8*)(rb + ((64 + lg * 16) ^ swz));
        }
    };
    auto MF = [&](int mh, int nh) {
        __builtin_amdgcn_s_setprio(1);
        #pragma unroll
        for (int f = 0; f < 4; ++f)
            #pragma unroll
            for (int g = 0; g < 2; ++g)
                #pragma unroll
                for (int ck = 0; ck < 2; ++ck)
                    acc[mh * 4 + f][nh * 2 + g] = __builtin_amdgcn_mfma_f32_16x16x32_bf16(
                        af[f][ck], bfr[nh * 2 + g][ck], acc[mh * 4 + f][nh * 2 + g], 0, 0, 0);
        __builtin_amdgcn_s_setprio(0);
    };
    #define BAR8()   do { __builtin_amdgcn_s_barrier(); __builtin_amdgcn_sched_barrier(0); } while (0)
    #define LGKM0()  do { asm volatile("s_waitcnt lgkmcnt(0)" ::: "memory"); __builtin_amdgcn_sched_barrier(0); } while (0)
    #define VM6()    do { asm volatile("s_waitcnt vmcnt(6)" ::: "memory"); __builtin_amdgcn_sched_barrier(0); } while (0)

    // prologue: T0 fully (8 loads), T1 first 3 halves (6 loads)
    stB(0, 0, 0); stB(0, 1, 0); stA(0, 0, 0); stA(0, 1, 0);
    stB(1, 0, 1); stB(1, 1, 1); stA(1, 0, 1);
    VM6();            // T0 complete (T1's 6 remain in flight)
    BAR8();

    for (int i = 0; i < 8; ++i) {           // 2 K-tiles / iter, 16 tiles total
        const bool st = (i < 7);
        // ph0 (T0=2i, buf0, quad 0,0)
        rdA(0, 0); rdB(0, 0);
        stA(2 * i + 1, 1, 1);               // T1's last half
        BAR8(); LGKM0(); MF(0, 0); BAR8();
        // ph1 (quad 0,1)
        rdB(1, 0);
        BAR8(); LGKM0(); MF(0, 1); BAR8();
        // ph2 (quad 1,0)
        rdA(1, 0);
        if (st) stB(2 * i + 2, 0, 0);
        BAR8(); LGKM0(); MF(1, 0); BAR8();
        // ph3 (quad 1,1) -- end: T1 guaranteed staged
        if (st) { stB(2 * i + 2, 1, 0); stA(2 * i + 2, 0, 0); }
        BAR8(); LGKM0(); MF(1, 1);
        VM6(); BAR8();
        // ph4 (T1=2i+1, buf1, quad 0,0)
        rdA(0, 1); rdB(0, 1);
        if (st) stA(2 * i + 2, 1, 0);
        BAR8(); LGKM0(); MF(0, 0); BAR8();
        // ph5 (quad 0,1)
        rdB(1, 1);
        BAR8(); LGKM0(); MF(0, 1); BAR8();
        // ph6 (quad 1,0)
        rdA(1, 1);
        if (st) stB(2 * i + 3, 0, 1);
        BAR8(); LGKM0(); MF(1, 0); BAR8();
        // ph7 (quad 1,1) -- end: next T0 guaranteed staged
        if (st) { stB(2 * i + 3, 1, 1); stA(2 * i + 3, 0, 1); }
        BAR8(); LGKM0(); MF(1, 1);
        VM6(); BAR8();
    }
    #undef BAR8
    #undef LGKM0
    #undef VM6

    // ---- epilogue ----
    if (n0 >= 2 * CC) {
        // V region: write transposed Vt[b][h][d][n], 8B stores
        #pragma unroll
        for (int fm = 0; fm < 8; ++fm) {
            const int row0 = m0 + wm * 128 + fm * 16 + lg * 4;
            const int bb = row0 >> 11, nn_ = row0 & (NN - 1);
            #pragma unroll
            for (int fn = 0; fn < 4; ++fn) {
                const int col = n0 - 2 * CC + wn * 64 + fn * 16 + l16;   // 0..1023
                const int hh = col >> 6, d = col & 63;
                short4v s4;
                #pragma unroll
                for (int r = 0; r < 4; ++r) s4[r] = pkbf(acc[fm][fn][r]);
                *(short4v*)&VtOut[((size_t)(bb * HH + hh) * DD + d) * NN + nn_] = s4;
            }
        }
    } else {
        // q/k region: RoPE (cos[d]==cos[d+32]); q scaled by D^-0.5*log2e
        const float qs = (n0 < CC) ? 0.125f * LOG2E : 1.0f;
        #pragma unroll
        for (int fm = 0; fm < 8; ++fm)
            #pragma unroll
            for (int r = 0; r < 4; ++r) {
                const int row = m0 + wm * 128 + fm * 16 + lg * 4 + r;
                #pragma unroll
                for (int j = 0; j < 2; ++j) {
                    const int d = j * 16 + l16;          // < 32
                    const float cv = cosp[(size_t)row * DD + d];
                    const float sv = sinp[(size_t)row * DD + d];
                    const float x1 = acc[fm][j][r];
                    const float x2 = acc[fm][j + 2][r];
                    const size_t cbase = (size_t)row * QKVN + n0 + wn * 64 + j * 16 + l16;
                    Cb[cbase]      = (bf16)((x1 * cv - x2 * sv) * qs);
                    Cb[cbase + 32] = (bf16)((x2 * cv + x1 * sv) * qs);
                }
            }
    }
}

// ---------------------------------------------------------------------------
// bf16 MFMA GEMM, double-buffered 2-phase (out-projection, fp32 output).
// ---------------------------------------------------------------------------
__global__ __launch_bounds__(256) void gemm3o(const bf16* __restrict__ A,
                                              const bf16* __restrict__ Bt,
                                              float* __restrict__ Cf) {
    __shared__ __align__(16) bf16 As[2][128 * 32];
    __shared__ __align__(16) bf16 Bs[2][128 * 32];
    const int tid = threadIdx.x, lane = tid & 63, wid = tid >> 6;
    const int wr = wid >> 1, wc = wid & 1, l16 = lane & 15, lg = lane >> 4;
    const int n0 = blockIdx.x * 128, m0 = blockIdx.y * 128;

    f32x4 acc[4][4];
    #pragma unroll
    for (int i = 0; i < 4; ++i)
        #pragma unroll
        for (int j = 0; j < 4; ++j) acc[i][j] = {0.f, 0.f, 0.f, 0.f};

    const int issue0 = wid * 2;
    const int sr0 = (issue0 * 1024 + lane * 16) >> 6;
    const int sc0 = ((issue0 * 1024 + lane * 16) & 63) >> 1;
    const int sr1 = ((issue0 + 1) * 1024 + lane * 16) >> 6;
    const int sc1 = (((issue0 + 1) * 1024 + lane * 16) & 63) >> 1;

    auto stage = [&](int k0, int bufi) {
        glds16(&A [(size_t)(m0 + sr0) * 1024 + k0 + sc0], (char*)&As[bufi][0] + issue0 * 1024);
        glds16(&Bt[(size_t)(n0 + sr0) * 1024 + k0 + sc0], (char*)&Bs[bufi][0] + issue0 * 1024);
        glds16(&A [(size_t)(m0 + sr1) * 1024 + k0 + sc1], (char*)&As[bufi][0] + (issue0 + 1) * 1024);
        glds16(&Bt[(size_t)(n0 + sr1) * 1024 + k0 + sc1], (char*)&Bs[bufi][0] + (issue0 + 1) * 1024);
    };

    stage(0, 0);
    for (int t = 0; t < 32; ++t) {
        const int cur = t & 1;
        __syncthreads();
        if (t + 1 < 32) stage((t + 1) * 32, cur ^ 1);
        short8 af[4], bfr[4];
        #pragma unroll
        for (int i = 0; i < 4; ++i) af[i]  = *(const short8*)((char*)&As[cur][0] + (wr * 64 + i * 16 + l16) * 64 + lg * 16);
        #pragma unroll
        for (int j = 0; j < 4; ++j) bfr[j] = *(const short8*)((char*)&Bs[cur][0] + (wc * 64 + j * 16 + l16) * 64 + lg * 16);
        #pragma unroll
        for (int i = 0; i < 4; ++i)
            #pragma unroll
            for (int j = 0; j < 4; ++j)
                acc[i][j] = __builtin_amdgcn_mfma_f32_16x16x32_bf16(af[i], bfr[j], acc[i][j], 0, 0, 0);
    }

    #pragma unroll
    for (int i = 0; i < 4; ++i)
        #pragma unroll
        for (int r = 0; r < 4; ++r) {
            const int row = m0 + wr * 64 + i * 16 + lg * 4 + r;
            #pragma unroll
            for (int j = 0; j < 4; ++j)
                Cf[(size_t)row * CC + n0 + wc * 64 + j * 16 + l16] = acc[i][j][r];
        }
}

// ---------------------------------------------------------------------------
// Flash attention v5: 3-way split-KV. 3072 blocks = 96 slots x 32 bh;
// slot -> (qt heavy-first, part 0..2). Un-normalized O partials + (m,l).
// Empty parts still write zero partials (replay safety: PartB/C alias d_out).
// ---------------------------------------------------------------------------
__global__ __launch_bounds__(256) void flash_mfma5(const bf16* __restrict__ QKV,
                                                   const bf16* __restrict__ Vt,
                                                   bf16* __restrict__ PartA,
                                                   bf16* __restrict__ PartB,
                                                   bf16* __restrict__ PartC,
                                                   float2* __restrict__ Mlb) {
    __shared__ __align__(16) bf16 Ks[2][4096];
    __shared__ __align__(16) bf16 Vs[2][4096];
    const int tid = threadIdx.x, lane = tid & 63, wid = tid >> 6;
    const int l16 = lane & 15, lg = lane >> 4;
    const int bid = blockIdx.x;                 // 3072 = 96 slots x 32 bh
    const int bh = bid & 31;                    // bid%8 spreads bh across XCDs
    const int slot = bid >> 5;                  // 0..95
    const int qt = 31 - slot / 3;               // heavy-first
    const int part = slot % 3;
    const int h = bh & (HH - 1), b = bh >> 4;
    const int wq0 = qt * 64 + wid * 16;
    const int nkt = qt + 1;
    const int t0 = (part * nkt) / 3;
    const int cnt = ((part + 1) * nkt) / 3 - t0;
    const int grow = b * NN + wq0 + l16;        // global q-row of lane's column

    const bf16* Kbase = QKV + (size_t)b * NN * QKVN + CC + h * DD;  // + k*QKVN
    const bf16* Vbase = Vt + (size_t)(b * HH + h) * DD * NN;        // + d*NN + k

    short8 qf[2];
    #pragma unroll
    for (int ch = 0; ch < 2; ++ch)
        qf[ch] = *(const short8*)&QKV[(size_t)grow * QKVN + h * DD + ch * 32 + lg * 8];

    f32x4 o[4];
    #pragma unroll
    for (int dn = 0; dn < 4; ++dn) o[dn] = {0.f, 0.f, 0.f, 0.f};
    float mx = -1e30f, ls = 0.f;

    const int a0 = (wid * 2) * 1024 + lane * 16, a1 = a0 + 1024;
    const int r0 = a0 >> 7, c0 = ((a0 & 127) ^ ((r0 & 7) << 4)) >> 1;
    const int r1 = a1 >> 7, c1 = ((a1 & 127) ^ ((r1 & 7) << 4)) >> 1;
    const bf16* kp0 = Kbase + (size_t)(t0 * 64 + r0) * QKVN + c0;
    const bf16* kp1 = Kbase + (size_t)(t0 * 64 + r1) * QKVN + c1;
    const bf16* vp0 = Vbase + (size_t)r0 * NN + t0 * 64 + c0;
    const bf16* vp1 = Vbase + (size_t)r1 * NN + t0 * 64 + c1;
    char* ldsK = (char*)&Ks[0][0] + wid * 2048;
    char* ldsV = (char*)&Vs[0][0] + wid * 2048;

    auto stage = [&](int par) {
        glds16(kp0, ldsK + par * 8192);
        glds16(kp1, ldsK + par * 8192 + 1024);
        glds16(vp0, ldsV + par * 8192);
        glds16(vp1, ldsV + par * 8192 + 1024);
        kp0 += 64 * QKVN; kp1 += 64 * QKVN; vp0 += 64; vp1 += 64;
    };

    if (cnt > 0) stage(0);
    for (int i = 0; i < cnt; ++i) {
        __syncthreads();                 // drains stage(i) vmcnt; buf[(i+1)&1] reads done
        if (i + 1 < cnt) stage((i + 1) & 1);
        const int cur = i & 1;
        const int kt = t0 + i;
        const int k0 = kt * 64;

        // ---- S^T = K Q^T : k rows, q cols ----
        f32x4 st[4];
        #pragma unroll
        for (int kc = 0; kc < 4; ++kc) st[kc] = {0.f, 0.f, 0.f, 0.f};
        __builtin_amdgcn_s_setprio(1);
        #pragma unroll
        for (int kc = 0; kc < 4; ++kc) {
            const int row = kc * 16 + l16;
            const char* rb = (const char*)&Ks[cur][0] + row * 128;
            const int sw = (row & 7) << 4;
            short8 kf0 = *(const short8*)(rb + ((lg * 16) ^ sw));
            short8 kf1 = *(const short8*)(rb + ((64 + lg * 16) ^ sw));
            st[kc] = __builtin_amdgcn_mfma_f32_16x16x32_bf16(kf0, qf[0], st[kc], 0, 0, 0);
            st[kc] = __builtin_amdgcn_mfma_f32_16x16x32_bf16(kf1, qf[1], st[kc], 0, 0, 0);
        }
        __builtin_amdgcn_s_setprio(0);

        if (kt == qt) {                  // diagonal tile: causal mask
            #pragma unroll
            for (int kc = 0; kc < 4; ++kc)
                #pragma unroll
                for (int r = 0; r < 4; ++r)
                    if (k0 + kc * 16 + lg * 4 + r > wq0 + l16) st[kc][r] = -1e30f;
        }

        // ---- online softmax (exp2 domain), defer-rescale ----
        float rm = fmaxf(fmaxf(st[0][0], st[0][1]), fmaxf(st[0][2], st[0][3]));
        #pragma unroll
        for (int kc = 1; kc < 4; ++kc)
            rm = fmaxf(rm, fmaxf(fmaxf(st[kc][0], st[kc][1]), fmaxf(st[kc][2], st[kc][3])));
        rm = fmaxf(rm, __shfl_xor(rm, 16, 64));
        rm = fmaxf(rm, __shfl_xor(rm, 32, 64));
        if (__any(rm > mx + 8.0f)) {
            const float mn = fmaxf(mx, rm);
            const float sc = __builtin_amdgcn_exp2f(mx - mn);
            ls *= sc;
            #pragma unroll
            for (int dn = 0; dn < 4; ++dn) {
                o[dn][0] *= sc; o[dn][1] *= sc; o[dn][2] *= sc; o[dn][3] *= sc;
            }
            mx = mn;
        }
        float rs = 0.f;
        #pragma unroll
        for (int kc = 0; kc < 4; ++kc)
            #pragma unroll
            for (int r = 0; r < 4; ++r) {
                const float p = __builtin_amdgcn_exp2f(st[kc][r] - mx);
                st[kc][r] = p; rs += p;
            }
        rs += __shfl_xor(rs, 16, 64);
        rs += __shfl_xor(rs, 32, 64);
        ls += rs;

        // ---- O^T += V^T P^T ----
        __builtin_amdgcn_s_setprio(1);
        #pragma unroll
        for (int kc = 0; kc < 4; ++kc) {
            short4v pf;
            pf[0] = pkbf(st[kc][0]); pf[1] = pkbf(st[kc][1]);
            pf[2] = pkbf(st[kc][2]); pf[3] = pkbf(st[kc][3]);
            #pragma unroll
            for (int dn = 0; dn < 4; ++dn) {
                const int row = dn * 16 + l16;
                short4v vf = *(const short4v*)((const char*)&Vs[cur][0] + row * 128
                                               + ((kc * 32 + lg * 8) ^ ((row & 7) << 4)));
                o[dn] = __builtin_amdgcn_mfma_f32_16x16x16bf16_1k(vf, pf, o[dn], 0, 0, 0);
            }
        }
        __builtin_amdgcn_s_setprio(0);
    }

    // ---- partial epilogue: UN-normalized O + (m,l); cnt==0 writes zeros ----
    if (lg == 0) Mlb[((size_t)(part * MM) + grow) * HH + h] = make_float2(mx, ls);
    bf16* dst = part == 0 ? PartA : (part == 1 ? PartB : PartC);
    const size_t rowb = (size_t)grow * CC + h * DD;
    #pragma unroll
    for (int dn = 0; dn < 4; ++dn) {
        short4v s4;
        s4[0] = pkbf(o[dn][0]); s4[1] = pkbf(o[dn][1]);
        s4[2] = pkbf(o[dn][2]); s4[3] = pkbf(o[dn][3]);
        *(short4v*)&dst[rowb + dn * 16 + lg * 4] = s4;
    }
}

// ---------------------------------------------------------------------------
// Combine the three KV-parts.
// ---------------------------------------------------------------------------
__global__ __launch_bounds__(256) void merge3(const bf16* __restrict__ pa,
                                              const bf16* __restrict__ pb,
                                              const bf16* __restrict__ pc,
                                              const float2* __restrict__ ml,
                                              bf16* __restrict__ outp) {
    const int idx = blockIdx.x * 256 + threadIdx.x;    // 524288 total
    const int row = idx >> 7;
    const int h = (idx & 127) >> 3;
    const float2 a  = ml[(size_t)row * HH + h];
    const float2 b_ = ml[((size_t)MM + row) * HH + h];
    const float2 c  = ml[((size_t)2 * MM + row) * HH + h];
    const float M = fmaxf(fmaxf(a.x, b_.x), c.x);
    const float w0 = (a.y  > 0.f) ? __builtin_amdgcn_exp2f(a.x  - M) : 0.f;
    const float w1 = (b_.y > 0.f) ? __builtin_amdgcn_exp2f(b_.x - M) : 0.f;
    const float w2 = (c.y  > 0.f) ? __builtin_amdgcn_exp2f(c.x  - M) : 0.f;
    const float inv = 1.f / (a.y * w0 + b_.y * w1 + c.y * w2);
    const float f0 = w0 * inv, f1 = w1 * inv, f2 = w2 * inv;
    const size_t off = (size_t)idx * 8;
    short8 va = *(const short8*)(pa + off);
    short8 vb = *(const short8*)(pb + off);
    short8 vc = *(const short8*)(pc + off);
    short8 ov;
    #pragma unroll
    for (int e = 0; e < 8; ++e)
        ov[e] = pkbf(b2f(va[e]) * f0 + b2f(vb[e]) * f1 + b2f(vc[e]) * f2);
    *(short8*)(outp + off) = ov;
}

// ---------------------------------------------------------------------------
extern "C" void kernel_launch(void* const* d_in, const int* in_sizes, int n_in,
                              void* d_out, int out_size, void* d_ws, size_t ws_size,
                              hipStream_t stream) {
    const float* hs   = (const float*)d_in[0];
    const float* cosp = (const float*)d_in[1];
    const float* sinp = (const float*)d_in[2];
    const float* Wq   = (const float*)d_in[3];
    const float* Wk   = (const float*)d_in[4];
    const float* Wv   = (const float*)d_in[5];
    const float* Wo   = (const float*)d_in[6];
    float* out = (float*)d_out;

    char* ws = (char*)d_ws;
    bf16* hsb   = (bf16*)(ws);                    //  8 MB [4096][1024]
    bf16* Wtqkv = (bf16*)(ws + (8  << 20));       //  6 MB [3072][1024]
    bf16* Wto   = (bf16*)(ws + (14 << 20));       //  2 MB [1024][1024]
    bf16* QKV   = (bf16*)(ws + (16 << 20));       // 24 MB [4096][3072] (q,k cols used)
    bf16* Vtb   = (bf16*)(ws + (40 << 20));       //  8 MB [2][16][64][2048]
    bf16* Abuf  = hsb;                            // alias: hs consumed by QKV GEMM
    float2* Mlb = (float2*)Wtqkv;                 // alias: Wtqkv dead after QKV GEMM (1.5 MB)
    bf16* PartB = (bf16*)out;                     // d_out as scratch until out-GEMM
    bf16* PartC = (bf16*)out + (size_t)MM * CC;   // second half of d_out

    convert_f32_bf16<<<MM * CC / 1024, 256, 0, stream>>>(hs, hsb);

    transpose4<<<dim3(32, 32, 4), dim3(32, 8), 0, stream>>>(Wq, Wk, Wv, Wo, Wtqkv, Wto);

    gemm8<<<dim3(QKVN / 256, MM / 256), 512, 0, stream>>>(
        hsb, Wtqkv, QKV, cosp, sinp, Vtb);

    flash_mfma5<<<3072, 256, 0, stream>>>(QKV, Vtb, Abuf, PartB, PartC, Mlb);

    merge3<<<2048, 256, 0, stream>>>(Abuf, PartB, PartC, Mlb, Abuf);

    gemm3o<<<dim3(CC / 128, MM / 128), 256, 0, stream>>>(Abuf, Wto, out);
}

// Round 9
// 126.892 us; speedup vs baseline: 9.3368x; 1.0010x over previous
//
#include <hip/hip_runtime.h>
#include <hip/hip_bf16.h>

typedef __hip_bfloat16 bf16;
typedef __attribute__((ext_vector_type(8))) short short8;
typedef __attribute__((ext_vector_type(4))) short short4v;
typedef __attribute__((ext_vector_type(4))) float f32x4;

#define BB 2
#define NN 2048
#define CC 1024
#define HH 16
#define DD 64
#define MM (BB*NN)     // 4096
#define QKVN 3072
#define LOG2E 1.44269504088896340736f

__device__ __forceinline__ void glds16(const void* g, void* l) {
    __builtin_amdgcn_global_load_lds((const __attribute__((address_space(1))) void*)g,
                                     (__attribute__((address_space(3))) void*)l, 16, 0, 0);
}
__device__ __forceinline__ short pkbf(float x) { bf16 t = (bf16)x; return *(short*)&t; }
__device__ __forceinline__ float b2f(short s) {
    return __uint_as_float(((unsigned)(unsigned short)s) << 16);
}

// ---------------------------------------------------------------------------
__global__ __launch_bounds__(256) void convert_f32_bf16(const float* __restrict__ in,
                                                        bf16* __restrict__ out) {
    int i = blockIdx.x * 256 + threadIdx.x;
    float4 v = ((const float4*)in)[i];
    short4v s;
    s.x = pkbf(v.x); s.y = pkbf(v.y); s.z = pkbf(v.z); s.w = pkbf(v.w);
    *((short4v*)out + i) = s;
}

// Transpose fp32 W[K][N] -> bf16 Wt[N][K]; z in 0..3 selects Wq,Wk,Wv,Wo
__global__ __launch_bounds__(256) void transpose4(const float* __restrict__ W0,
                                                  const float* __restrict__ W1,
                                                  const float* __restrict__ W2,
                                                  const float* __restrict__ W3,
                                                  bf16* __restrict__ Wtqkv,
                                                  bf16* __restrict__ Wto) {
    __shared__ float t[32][33];
    const int z = blockIdx.z;
    const float* W = z == 0 ? W0 : (z == 1 ? W1 : (z == 2 ? W2 : W3));
    bf16* dst = z < 3 ? Wtqkv + (size_t)z * CC * CC : Wto;
    const int tx = threadIdx.x, ty = threadIdx.y;
    const int x0 = blockIdx.x * 32, y0 = blockIdx.y * 32;
    #pragma unroll
    for (int i = 0; i < 4; ++i)
        t[ty + i * 8][tx] = W[(size_t)(y0 + ty + i * 8) * CC + x0 + tx];
    __syncthreads();
    #pragma unroll
    for (int i = 0; i < 4; ++i)
        dst[(size_t)(x0 + ty + i * 8) * CC + y0 + tx] = (bf16)t[tx][ty + i * 8];
}

// ---------------------------------------------------------------------------
// 8-phase 256x256 (BK=64) bf16 MFMA GEMM for the QKV projection (K=1024).
// v2: raw s_barrier + bare s_waitcnt (NO sched_barrier pins — m141 lesson).
// T2 XOR-swizzled LDS, T4 counted vmcnt(6) at phase-3/7 ends, T5 setprio.
// Epilogue: RoPE+log2e on q/k cols; V written transposed to VtOut.
// ---------------------------------------------------------------------------
__global__ __launch_bounds__(512, 2) void gemm8(const bf16* __restrict__ A,
                                                const bf16* __restrict__ Bt,
                                                bf16* __restrict__ Cb,
                                                const float* __restrict__ cosp,
                                                const float* __restrict__ sinp,
                                                bf16* __restrict__ VtOut) {
    __shared__ __align__(16) bf16 As[2][256 * 64];   // 64 KB
    __shared__ __align__(16) bf16 Bs[2][256 * 64];   // 64 KB
    const int tid = threadIdx.x, lane = tid & 63, wid = tid >> 6;
    const int wm = wid >> 2, wn = wid & 3, l16 = lane & 15, lg = lane >> 4;
    const int n0 = blockIdx.x * 256, m0 = blockIdx.y * 256;

    f32x4 acc[8][4];
    #pragma unroll
    for (int i = 0; i < 8; ++i)
        #pragma unroll
        for (int j = 0; j < 4; ++j) acc[i][j] = {0.f, 0.f, 0.f, 0.f};

    // staging: per half-tile (128 rows x 64 cols), 2 glds16/thread, pre-swizzled src
    const int srow = lane >> 3;                                     // 0..7
    const int sce  = (((lane & 7) * 16) ^ ((lane >> 3) << 4)) >> 1; // swizzled elem col
    auto stA = [&](int t, int hf, int bi) {
        #pragma unroll
        for (int j = 0; j < 2; ++j) {
            const int rl = hf * 128 + (wid * 2 + j) * 8;
            glds16(&A[(size_t)(m0 + rl + srow) * 1024 + t * 64 + sce], (void*)&As[bi][rl * 64]);
        }
    };
    auto stB = [&](int t, int hf, int bi) {
        #pragma unroll
        for (int j = 0; j < 2; ++j) {
            const int rl = hf * 128 + (wid * 2 + j) * 8;
            glds16(&Bt[(size_t)(n0 + rl + srow) * 1024 + t * 64 + sce], (void*)&Bs[bi][rl * 64]);
        }
    };

    short8 af[4][2], bfr[4][2];
    const int swz = (l16 & 7) << 4;
    auto rdA = [&](int mh, int bi) {
        #pragma unroll
        for (int f = 0; f < 4; ++f) {
            const char* rb = (const char*)&As[bi][0] + (wm * 128 + (mh * 4 + f) * 16 + l16) * 128;
            af[f][0] = *(const short8*)(rb + ((lg * 16) ^ swz));
            af[f][1] = *(const short8*)(rb + ((64 + lg * 16) ^ swz));
        }
    };
    auto rdB = [&](int nh, int bi) {
        #pragma unroll
        for (int f = 0; f < 2; ++f) {
            const char* rb = (const char*)&Bs[bi][0] + (wn * 64 + (nh * 2 + f) * 16 + l16) * 128;
            bfr[nh * 2 + f][0] = *(const short8*)(rb + ((lg * 16) ^ swz));
            bfr[nh * 2 + f][1] = *(const short8*)(rb + ((64 + lg * 16) ^ swz));
        }
    };
    auto MF = [&](int mh, int nh) {
        __builtin_amdgcn_s_setprio(1);
        #pragma unroll
        for (int f = 0; f < 4; ++f)
            #pragma unroll
            for (int g = 0; g < 2; ++g)
                #pragma unroll
                for (int ck = 0; ck < 2; ++ck)
                    acc[mh * 4 + f][nh * 2 + g] = __builtin_amdgcn_mfma_f32_16x16x32_bf16(
                        af[f][ck], bfr[nh * 2 + g][ck], acc[mh * 4 + f][nh * 2 + g], 0, 0, 0);
        __builtin_amdgcn_s_setprio(0);
    };
    #define BAR8()   __builtin_amdgcn_s_barrier()
    #define LGKM0()  asm volatile("s_waitcnt lgkmcnt(0)" ::: "memory")
    #define VM6()    asm volatile("s_waitcnt vmcnt(6)" ::: "memory")

    // prologue: T0 fully (8 loads), T1 first 3 halves (6 loads)
    stB(0, 0, 0); stB(0, 1, 0); stA(0, 0, 0); stA(0, 1, 0);
    stB(1, 0, 1); stB(1, 1, 1); stA(1, 0, 1);
    VM6();            // T0 complete (T1's 6 remain in flight)
    BAR8();

    for (int i = 0; i < 8; ++i) {           // 2 K-tiles / iter, 16 tiles total
        const bool st = (i < 7);
        // ph0 (T0=2i, buf0, quad 0,0)
        rdA(0, 0); rdB(0, 0);
        stA(2 * i + 1, 1, 1);               // T1's last half
        BAR8(); LGKM0(); MF(0, 0); BAR8();
        // ph1 (quad 0,1)
        rdB(1, 0);
        BAR8(); LGKM0(); MF(0, 1); BAR8();
        // ph2 (quad 1,0)
        rdA(1, 0);
        if (st) stB(2 * i + 2, 0, 0);
        BAR8(); LGKM0(); MF(1, 0); BAR8();
        // ph3 (quad 1,1) -- end: T1 guaranteed staged
        if (st) { stB(2 * i + 2, 1, 0); stA(2 * i + 2, 0, 0); }
        BAR8(); LGKM0(); MF(1, 1);
        VM6(); BAR8();
        // ph4 (T1=2i+1, buf1, quad 0,0)
        rdA(0, 1); rdB(0, 1);
        if (st) stA(2 * i + 2, 1, 0);
        BAR8(); LGKM0(); MF(0, 0); BAR8();
        // ph5 (quad 0,1)
        rdB(1, 1);
        BAR8(); LGKM0(); MF(0, 1); BAR8();
        // ph6 (quad 1,0)
        rdA(1, 1);
        if (st) stB(2 * i + 3, 0, 1);
        BAR8(); LGKM0(); MF(1, 0); BAR8();
        // ph7 (quad 1,1) -- end: next T0 guaranteed staged
        if (st) { stB(2 * i + 3, 1, 1); stA(2 * i + 3, 0, 1); }
        BAR8(); LGKM0(); MF(1, 1);
        VM6(); BAR8();
    }
    #undef BAR8
    #undef LGKM0
    #undef VM6

    // ---- epilogue ----
    if (n0 >= 2 * CC) {
        // V region: write transposed Vt[b][h][d][n], 8B stores
        #pragma unroll
        for (int fm = 0; fm < 8; ++fm) {
            const int row0 = m0 + wm * 128 + fm * 16 + lg * 4;
            const int bb = row0 >> 11, nn_ = row0 & (NN - 1);
            #pragma unroll
            for (int fn = 0; fn < 4; ++fn) {
                const int col = n0 - 2 * CC + wn * 64 + fn * 16 + l16;   // 0..1023
                const int hh = col >> 6, d = col & 63;
                short4v s4;
                #pragma unroll
                for (int r = 0; r < 4; ++r) s4[r] = pkbf(acc[fm][fn][r]);
                *(short4v*)&VtOut[((size_t)(bb * HH + hh) * DD + d) * NN + nn_] = s4;
            }
        }
    } else {
        // q/k region: RoPE (cos[d]==cos[d+32]); q scaled by D^-0.5*log2e
        const float qs = (n0 < CC) ? 0.125f * LOG2E : 1.0f;
        #pragma unroll
        for (int fm = 0; fm < 8; ++fm)
            #pragma unroll
            for (int r = 0; r < 4; ++r) {
                const int row = m0 + wm * 128 + fm * 16 + lg * 4 + r;
                #pragma unroll
                for (int j = 0; j < 2; ++j) {
                    const int d = j * 16 + l16;          // < 32
                    const float cv = cosp[(size_t)row * DD + d];
                    const float sv = sinp[(size_t)row * DD + d];
                    const float x1 = acc[fm][j][r];
                    const float x2 = acc[fm][j + 2][r];
                    const size_t cbase = (size_t)row * QKVN + n0 + wn * 64 + j * 16 + l16;
                    Cb[cbase]      = (bf16)((x1 * cv - x2 * sv) * qs);
                    Cb[cbase + 32] = (bf16)((x2 * cv + x1 * sv) * qs);
                }
            }
    }
}

// ---------------------------------------------------------------------------
// bf16 MFMA GEMM, double-buffered 2-phase (out-projection, fp32 output).
// ---------------------------------------------------------------------------
__global__ __launch_bounds__(256) void gemm3o(const bf16* __restrict__ A,
                                              const bf16* __restrict__ Bt,
                                              float* __restrict__ Cf) {
    __shared__ __align__(16) bf16 As[2][128 * 32];
    __shared__ __align__(16) bf16 Bs[2][128 * 32];
    const int tid = threadIdx.x, lane = tid & 63, wid = tid >> 6;
    const int wr = wid >> 1, wc = wid & 1, l16 = lane & 15, lg = lane >> 4;
    const int n0 = blockIdx.x * 128, m0 = blockIdx.y * 128;

    f32x4 acc[4][4];
    #pragma unroll
    for (int i = 0; i < 4; ++i)
        #pragma unroll
        for (int j = 0; j < 4; ++j) acc[i][j] = {0.f, 0.f, 0.f, 0.f};

    const int issue0 = wid * 2;
    const int sr0 = (issue0 * 1024 + lane * 16) >> 6;
    const int sc0 = ((issue0 * 1024 + lane * 16) & 63) >> 1;
    const int sr1 = ((issue0 + 1) * 1024 + lane * 16) >> 6;
    const int sc1 = (((issue0 + 1) * 1024 + lane * 16) & 63) >> 1;

    auto stage = [&](int k0, int bufi) {
        glds16(&A [(size_t)(m0 + sr0) * 1024 + k0 + sc0], (char*)&As[bufi][0] + issue0 * 1024);
        glds16(&Bt[(size_t)(n0 + sr0) * 1024 + k0 + sc0], (char*)&Bs[bufi][0] + issue0 * 1024);
        glds16(&A [(size_t)(m0 + sr1) * 1024 + k0 + sc1], (char*)&As[bufi][0] + (issue0 + 1) * 1024);
        glds16(&Bt[(size_t)(n0 + sr1) * 1024 + k0 + sc1], (char*)&Bs[bufi][0] + (issue0 + 1) * 1024);
    };

    stage(0, 0);
    for (int t = 0; t < 32; ++t) {
        const int cur = t & 1;
        __syncthreads();
        if (t + 1 < 32) stage((t + 1) * 32, cur ^ 1);
        short8 af[4], bfr[4];
        #pragma unroll
        for (int i = 0; i < 4; ++i) af[i]  = *(const short8*)((char*)&As[cur][0] + (wr * 64 + i * 16 + l16) * 64 + lg * 16);
        #pragma unroll
        for (int j = 0; j < 4; ++j) bfr[j] = *(const short8*)((char*)&Bs[cur][0] + (wc * 64 + j * 16 + l16) * 64 + lg * 16);
        #pragma unroll
        for (int i = 0; i < 4; ++i)
            #pragma unroll
            for (int j = 0; j < 4; ++j)
                acc[i][j] = __builtin_amdgcn_mfma_f32_16x16x32_bf16(af[i], bfr[j], acc[i][j], 0, 0, 0);
    }

    #pragma unroll
    for (int i = 0; i < 4; ++i)
        #pragma unroll
        for (int r = 0; r < 4; ++r) {
            const int row = m0 + wr * 64 + i * 16 + lg * 4 + r;
            #pragma unroll
            for (int j = 0; j < 4; ++j)
                Cf[(size_t)row * CC + n0 + wc * 64 + j * 16 + l16] = acc[i][j][r];
        }
}

// ---------------------------------------------------------------------------
// Flash attention v5: 3-way split-KV (unchanged from round 8).
// ---------------------------------------------------------------------------
__global__ __launch_bounds__(256) void flash_mfma5(const bf16* __restrict__ QKV,
                                                   const bf16* __restrict__ Vt,
                                                   bf16* __restrict__ PartA,
                                                   bf16* __restrict__ PartB,
                                                   bf16* __restrict__ PartC,
                                                   float2* __restrict__ Mlb) {
    __shared__ __align__(16) bf16 Ks[2][4096];
    __shared__ __align__(16) bf16 Vs[2][4096];
    const int tid = threadIdx.x, lane = tid & 63, wid = tid >> 6;
    const int l16 = lane & 15, lg = lane >> 4;
    const int bid = blockIdx.x;                 // 3072 = 96 slots x 32 bh
    const int bh = bid & 31;                    // bid%8 spreads bh across XCDs
    const int slot = bid >> 5;                  // 0..95
    const int qt = 31 - slot / 3;               // heavy-first
    const int part = slot % 3;
    const int h = bh & (HH - 1), b = bh >> 4;
    const int wq0 = qt * 64 + wid * 16;
    const int nkt = qt + 1;
    const int t0 = (part * nkt) / 3;
    const int cnt = ((part + 1) * nkt) / 3 - t0;
    const int grow = b * NN + wq0 + l16;        // global q-row of lane's column

    const bf16* Kbase = QKV + (size_t)b * NN * QKVN + CC + h * DD;  // + k*QKVN
    const bf16* Vbase = Vt + (size_t)(b * HH + h) * DD * NN;        // + d*NN + k

    short8 qf[2];
    #pragma unroll
    for (int ch = 0; ch < 2; ++ch)
        qf[ch] = *(const short8*)&QKV[(size_t)grow * QKVN + h * DD + ch * 32 + lg * 8];

    f32x4 o[4];
    #pragma unroll
    for (int dn = 0; dn < 4; ++dn) o[dn] = {0.f, 0.f, 0.f, 0.f};
    float mx = -1e30f, ls = 0.f;

    const int a0 = (wid * 2) * 1024 + lane * 16, a1 = a0 + 1024;
    const int r0 = a0 >> 7, c0 = ((a0 & 127) ^ ((r0 & 7) << 4)) >> 1;
    const int r1 = a1 >> 7, c1 = ((a1 & 127) ^ ((r1 & 7) << 4)) >> 1;
    const bf16* kp0 = Kbase + (size_t)(t0 * 64 + r0) * QKVN + c0;
    const bf16* kp1 = Kbase + (size_t)(t0 * 64 + r1) * QKVN + c1;
    const bf16* vp0 = Vbase + (size_t)r0 * NN + t0 * 64 + c0;
    const bf16* vp1 = Vbase + (size_t)r1 * NN + t0 * 64 + c1;
    char* ldsK = (char*)&Ks[0][0] + wid * 2048;
    char* ldsV = (char*)&Vs[0][0] + wid * 2048;

    auto stage = [&](int par) {
        glds16(kp0, ldsK + par * 8192);
        glds16(kp1, ldsK + par * 8192 + 1024);
        glds16(vp0, ldsV + par * 8192);
        glds16(vp1, ldsV + par * 8192 + 1024);
        kp0 += 64 * QKVN; kp1 += 64 * QKVN; vp0 += 64; vp1 += 64;
    };

    if (cnt > 0) stage(0);
    for (int i = 0; i < cnt; ++i) {
        __syncthreads();                 // drains stage(i) vmcnt; buf[(i+1)&1] reads done
        if (i + 1 < cnt) stage((i + 1) & 1);
        const int cur = i & 1;
        const int kt = t0 + i;
        const int k0 = kt * 64;

        // ---- S^T = K Q^T : k rows, q cols ----
        f32x4 st[4];
        #pragma unroll
        for (int kc = 0; kc < 4; ++kc) st[kc] = {0.f, 0.f, 0.f, 0.f};
        __builtin_amdgcn_s_setprio(1);
        #pragma unroll
        for (int kc = 0; kc < 4; ++kc) {
            const int row = kc * 16 + l16;
            const char* rb = (const char*)&Ks[cur][0] + row * 128;
            const int sw = (row & 7) << 4;
            short8 kf0 = *(const short8*)(rb + ((lg * 16) ^ sw));
            short8 kf1 = *(const short8*)(rb + ((64 + lg * 16) ^ sw));
            st[kc] = __builtin_amdgcn_mfma_f32_16x16x32_bf16(kf0, qf[0], st[kc], 0, 0, 0);
            st[kc] = __builtin_amdgcn_mfma_f32_16x16x32_bf16(kf1, qf[1], st[kc], 0, 0, 0);
        }
        __builtin_amdgcn_s_setprio(0);

        if (kt == qt) {                  // diagonal tile: causal mask
            #pragma unroll
            for (int kc = 0; kc < 4; ++kc)
                #pragma unroll
                for (int r = 0; r < 4; ++r)
                    if (k0 + kc * 16 + lg * 4 + r > wq0 + l16) st[kc][r] = -1e30f;
        }

        // ---- online softmax (exp2 domain), defer-rescale ----
        float rm = fmaxf(fmaxf(st[0][0], st[0][1]), fmaxf(st[0][2], st[0][3]));
        #pragma unroll
        for (int kc = 1; kc < 4; ++kc)
            rm = fmaxf(rm, fmaxf(fmaxf(st[kc][0], st[kc][1]), fmaxf(st[kc][2], st[kc][3])));
        rm = fmaxf(rm, __shfl_xor(rm, 16, 64));
        rm = fmaxf(rm, __shfl_xor(rm, 32, 64));
        if (__any(rm > mx + 8.0f)) {
            const float mn = fmaxf(mx, rm);
            const float sc = __builtin_amdgcn_exp2f(mx - mn);
            ls *= sc;
            #pragma unroll
            for (int dn = 0; dn < 4; ++dn) {
                o[dn][0] *= sc; o[dn][1] *= sc; o[dn][2] *= sc; o[dn][3] *= sc;
            }
            mx = mn;
        }
        float rs = 0.f;
        #pragma unroll
        for (int kc = 0; kc < 4; ++kc)
            #pragma unroll
            for (int r = 0; r < 4; ++r) {
                const float p = __builtin_amdgcn_exp2f(st[kc][r] - mx);
                st[kc][r] = p; rs += p;
            }
        rs += __shfl_xor(rs, 16, 64);
        rs += __shfl_xor(rs, 32, 64);
        ls += rs;

        // ---- O^T += V^T P^T ----
        __builtin_amdgcn_s_setprio(1);
        #pragma unroll
        for (int kc = 0; kc < 4; ++kc) {
            short4v pf;
            pf[0] = pkbf(st[kc][0]); pf[1] = pkbf(st[kc][1]);
            pf[2] = pkbf(st[kc][2]); pf[3] = pkbf(st[kc][3]);
            #pragma unroll
            for (int dn = 0; dn < 4; ++dn) {
                const int row = dn * 16 + l16;
                short4v vf = *(const short4v*)((const char*)&Vs[cur][0] + row * 128
                                               + ((kc * 32 + lg * 8) ^ ((row & 7) << 4)));
                o[dn] = __builtin_amdgcn_mfma_f32_16x16x16bf16_1k(vf, pf, o[dn], 0, 0, 0);
            }
        }
        __builtin_amdgcn_s_setprio(0);
    }

    // ---- partial epilogue: UN-normalized O + (m,l); cnt==0 writes zeros ----
    if (lg == 0) Mlb[((size_t)(part * MM) + grow) * HH + h] = make_float2(mx, ls);
    bf16* dst = part == 0 ? PartA : (part == 1 ? PartB : PartC);
    const size_t rowb = (size_t)grow * CC + h * DD;
    #pragma unroll
    for (int dn = 0; dn < 4; ++dn) {
        short4v s4;
        s4[0] = pkbf(o[dn][0]); s4[1] = pkbf(o[dn][1]);
        s4[2] = pkbf(o[dn][2]); s4[3] = pkbf(o[dn][3]);
        *(short4v*)&dst[rowb + dn * 16 + lg * 4] = s4;
    }
}

// ---------------------------------------------------------------------------
// Combine the three KV-parts.
// ---------------------------------------------------------------------------
__global__ __launch_bounds__(256) void merge3(const bf16* __restrict__ pa,
                                              const bf16* __restrict__ pb,
                                              const bf16* __restrict__ pc,
                                              const float2* __restrict__ ml,
                                              bf16* __restrict__ outp) {
    const int idx = blockIdx.x * 256 + threadIdx.x;    // 524288 total
    const int row = idx >> 7;
    const int h = (idx & 127) >> 3;
    const float2 a  = ml[(size_t)row * HH + h];
    const float2 b_ = ml[((size_t)MM + row) * HH + h];
    const float2 c  = ml[((size_t)2 * MM + row) * HH + h];
    const float M = fmaxf(fmaxf(a.x, b_.x), c.x);
    const float w0 = (a.y  > 0.f) ? __builtin_amdgcn_exp2f(a.x  - M) : 0.f;
    const float w1 = (b_.y > 0.f) ? __builtin_amdgcn_exp2f(b_.x - M) : 0.f;
    const float w2 = (c.y  > 0.f) ? __builtin_amdgcn_exp2f(c.x  - M) : 0.f;
    const float inv = 1.f / (a.y * w0 + b_.y * w1 + c.y * w2);
    const float f0 = w0 * inv, f1 = w1 * inv, f2 = w2 * inv;
    const size_t off = (size_t)idx * 8;
    short8 va = *(const short8*)(pa + off);
    short8 vb = *(const short8*)(pb + off);
    short8 vc = *(const short8*)(pc + off);
    short8 ov;
    #pragma unroll
    for (int e = 0; e < 8; ++e)
        ov[e] = pkbf(b2f(va[e]) * f0 + b2f(vb[e]) * f1 + b2f(vc[e]) * f2);
    *(short8*)(outp + off) = ov;
}

// ---------------------------------------------------------------------------
extern "C" void kernel_launch(void* const* d_in, const int* in_sizes, int n_in,
                              void* d_out, int out_size, void* d_ws, size_t ws_size,
                              hipStream_t stream) {
    const float* hs   = (const float*)d_in[0];
    const float* cosp = (const float*)d_in[1];
    const float* sinp = (const float*)d_in[2];
    const float* Wq   = (const float*)d_in[3];
    const float* Wk   = (const float*)d_in[4];
    const float* Wv   = (const float*)d_in[5];
    const float* Wo   = (const float*)d_in[6];
    float* out = (float*)d_out;

    char* ws = (char*)d_ws;
    bf16* hsb   = (bf16*)(ws);                    //  8 MB [4096][1024]
    bf16* Wtqkv = (bf16*)(ws + (8  << 20));       //  6 MB [3072][1024]
    bf16* Wto   = (bf16*)(ws + (14 << 20));       //  2 MB [1024][1024]
    bf16* QKV   = (bf16*)(ws + (16 << 20));       // 24 MB [4096][3072] (q,k cols used)
    bf16* Vtb   = (bf16*)(ws + (40 << 20));       //  8 MB [2][16][64][2048]
    bf16* Abuf  = hsb;                            // alias: hs consumed by QKV GEMM
    float2* Mlb = (float2*)Wtqkv;                 // alias: Wtqkv dead after QKV GEMM (1.5 MB)
    bf16* PartB = (bf16*)out;                     // d_out as scratch until out-GEMM
    bf16* PartC = (bf16*)out + (size_t)MM * CC;   // second half of d_out

    convert_f32_bf16<<<MM * CC / 1024, 256, 0, stream>>>(hs, hsb);

    transpose4<<<dim3(32, 32, 4), dim3(32, 8), 0, stream>>>(Wq, Wk, Wv, Wo, Wtqkv, Wto);

    gemm8<<<dim3(QKVN / 256, MM / 256), 512, 0, stream>>>(
        hsb, Wtqkv, QKV, cosp, sinp, Vtb);

    flash_mfma5<<<3072, 256, 0, stream>>>(QKV, Vtb, Abuf, PartB, PartC, Mlb);

    merge3<<<2048, 256, 0, stream>>>(Abuf, PartB, PartC, Mlb, Abuf);

    gemm3o<<<dim3(CC / 128, MM / 128), 256, 0, stream>>>(Abuf, Wto, out);
}